// Round 14
// baseline (3154.217 us; speedup 1.0000x reference)
//
#include <hip/hip_runtime.h>
#include <hip/hip_bf16.h>
#include <math.h>

#define BB 4
#define TT 1024
#define VV 50257
#define VPAD2 50432
#define CC 768
#define HH 12
#define DD 64
#define LL 12
#define FFH 3072
#define MROWS (BB*TT)   // 4096
#define QBLK 128
#define KVBLK 64
#define NPART (VPAD2 / 64)        // 788 partials per row

typedef __bf16 bf16x8 __attribute__((ext_vector_type(8)));
typedef float  f32x4  __attribute__((ext_vector_type(4)));
typedef unsigned int u32;
#define AS1 __attribute__((address_space(1)))
#define AS3 __attribute__((address_space(3)))

static __device__ __forceinline__ void gload_lds16(const void* g, void* l) {
    __builtin_amdgcn_global_load_lds((const AS1 u32*)g, (AS3 u32*)l, 16, 0, 0);
}

// stage one 128x64 bf16 tile pair into linear LDS, source pre-swizzled (4 waves)
static __device__ __forceinline__ void stage_tile(const __hip_bfloat16* __restrict__ A,
                                                  const __hip_bfloat16* __restrict__ Bt,
                                                  int Kld, int k0, int bm, int bn,
                                                  int w, int l, char* As, char* Bs) {
    #pragma unroll
    for (int it = 0; it < 4; it++) {
        int chunk = w * 4 + it;
        int o = chunk * 1024 + l * 16;
        int row = o >> 7;
        int cb = (o & 127) ^ ((row & 7) << 4);
        gload_lds16(A + (size_t)(bm + row) * Kld + k0 + (cb >> 1), As + chunk * 1024);
        gload_lds16(Bt + (size_t)(bn + row) * Kld + k0 + (cb >> 1), Bs + chunk * 1024);
    }
}

// stage A(128x64) + B(64x64) for the n64 tile (4 waves)
static __device__ __forceinline__ void stage_tile_n64(const __hip_bfloat16* __restrict__ A,
                                                      const __hip_bfloat16* __restrict__ Bt,
                                                      int Kld, int k0, int bm, int bn,
                                                      int w, int l, char* As, char* Bs) {
    #pragma unroll
    for (int it = 0; it < 4; it++) {
        int chunk = w * 4 + it;
        int o = chunk * 1024 + l * 16;
        int row = o >> 7;
        int cb = (o & 127) ^ ((row & 7) << 4);
        gload_lds16(A + (size_t)(bm + row) * Kld + k0 + (cb >> 1), As + chunk * 1024);
    }
    #pragma unroll
    for (int it = 0; it < 2; it++) {
        int chunk = w * 2 + it;
        int o = chunk * 1024 + l * 16;
        int row = o >> 7;
        int cb = (o & 127) ^ ((row & 7) << 4);
        gload_lds16(Bt + (size_t)(bn + row) * Kld + k0 + (cb >> 1), Bs + chunk * 1024);
    }
}

// stage one 128-row x 64-col half-tile of ONE tensor (16KB; 512 threads x 2 loads)
static __device__ __forceinline__ void stage_half(const __hip_bfloat16* __restrict__ src,
                                                  int Kld, int k0, int rowbase,
                                                  char* dst, int w, int l) {
    #pragma unroll
    for (int it = 0; it < 2; it++) {
        int chunk = w * 2 + it;
        int o = chunk * 1024 + l * 16;
        int row = o >> 7;
        int cb = (o & 127) ^ ((row & 7) << 4);
        gload_lds16(src + (size_t)(rowbase + row) * Kld + k0 + (cb >> 1), dst + chunk * 1024);
    }
}

// ---------------- embedding (bf16 residual stream)
__global__ void embed_kernel(const int* __restrict__ x, const float* __restrict__ tok,
                             const float* __restrict__ pos,
                             __hip_bfloat16* __restrict__ hb) {
    int idx = blockIdx.x * 256 + threadIdx.x;
    if (idx >= MROWS * CC) return;
    int row = idx / CC, c = idx - row * CC;
    int id = x[row];
    hb[idx] = __float2bfloat16(tok[(size_t)id * CC + c] + pos[(size_t)id * CC + c]);
}

// ---------------- convert + transpose weights
__global__ __launch_bounds__(256) void cvtT_mat(const float* __restrict__ in,
                                                __hip_bfloat16* __restrict__ out,
                                                int K, int Nin,
                                                size_t ibs, size_t obs) {
    __shared__ float t[32][33];
    const float* ip = in + blockIdx.z * ibs;
    __hip_bfloat16* op = out + blockIdx.z * obs;
    int n0 = blockIdx.x * 32, k0 = blockIdx.y * 32;
    int tx = threadIdx.x & 31, ty = threadIdx.x >> 5;
    #pragma unroll
    for (int i = 0; i < 4; i++) {
        int k = k0 + ty + i * 8, n = n0 + tx;
        t[ty + i * 8][tx] = (n < Nin) ? ip[(size_t)k * Nin + n] : 0.f;
    }
    __syncthreads();
    #pragma unroll
    for (int i = 0; i < 4; i++) {
        int n = n0 + ty + i * 8, k = k0 + tx;
        op[(size_t)n * K + k] = __float2bfloat16(t[tx][ty + i * 8]);
    }
}

__global__ __launch_bounds__(256) void cvtT_qkv(const float* __restrict__ Wk,
                                                const float* __restrict__ Wq,
                                                const float* __restrict__ Wv,
                                                __hip_bfloat16* __restrict__ kT,
                                                __hip_bfloat16* __restrict__ qT,
                                                __hip_bfloat16* __restrict__ vT) {
    int z = blockIdx.z;
    int tensor = z / 144, lh = z % 144;
    int l = lh / HH, hh = lh % HH;
    const float* in = (tensor == 0 ? Wk : tensor == 1 ? Wq : Wv) + (size_t)lh * CC * DD;
    __hip_bfloat16* out = (tensor == 0 ? kT : tensor == 1 ? qT : vT)
                          + ((size_t)l * CC + hh * DD) * CC;
    __shared__ float t[32][33];
    int c0 = blockIdx.x * 32, d0 = blockIdx.y * 32;
    int tx = threadIdx.x & 31, ty = threadIdx.x >> 5;
    #pragma unroll
    for (int i = 0; i < 4; i++)
        t[ty + i * 8][tx] = in[(size_t)(c0 + ty + i * 8) * DD + d0 + tx];
    __syncthreads();
    #pragma unroll
    for (int i = 0; i < 4; i++)
        out[(size_t)(d0 + ty + i * 8) * CC + c0 + tx] = __float2bfloat16(t[tx][ty + i * 8]);
}

// ---------------- MFMA GEMM 128x128 dbuf + LDS-staged coalesced epilogue.
__global__ __launch_bounds__(256) void gemm_mfma(const __hip_bfloat16* __restrict__ A,
                                                 const __hip_bfloat16* __restrict__ Bt,
                                                 const float* __restrict__ bias,
                                                 float* __restrict__ Cf,
                                                 __hip_bfloat16* __restrict__ Cb,
                                                 int M, int N, int K, int relu) {
    __shared__ __align__(16) char smem[65536];
    int tid = threadIdx.x;
    int l = tid & 63, w = tid >> 6;
    int wr = w >> 1, wc = w & 1;
    int bm = blockIdx.y * 128, bn = blockIdx.x * 128;

    f32x4 acc[4][4] = {};

    stage_tile(A, Bt, K, 0, bm, bn, w, l, smem, smem + 32768);
    int p = 0;
    for (int k0 = 0; k0 < K; k0 += 64) {
        __syncthreads();
        if (k0 + 64 < K)
            stage_tile(A, Bt, K, k0 + 64, bm, bn, w, l,
                       smem + (p ^ 1) * 16384, smem + 32768 + (p ^ 1) * 16384);
        const char* Ab = smem + p * 16384;
        const char* Bb = smem + 32768 + p * 16384;
        #pragma unroll
        for (int ks = 0; ks < 2; ks++) {
            bf16x8 af[4], bfr[4];
            #pragma unroll
            for (int i = 0; i < 4; i++) {
                int row = wr * 64 + i * 16 + (l & 15);
                int cb = (ks * 64 + (l >> 4) * 16) ^ ((row & 7) << 4);
                af[i] = *(const bf16x8*)(Ab + row * 128 + cb);
            }
            #pragma unroll
            for (int j = 0; j < 4; j++) {
                int row = wc * 64 + j * 16 + (l & 15);
                int cb = (ks * 64 + (l >> 4) * 16) ^ ((row & 7) << 4);
                bfr[j] = *(const bf16x8*)(Bb + row * 128 + cb);
            }
            #pragma unroll
            for (int i = 0; i < 4; i++)
                #pragma unroll
                for (int j = 0; j < 4; j++)
                    acc[i][j] = __builtin_amdgcn_mfma_f32_16x16x32_bf16(af[i], bfr[j], acc[i][j], 0, 0, 0);
        }
        p ^= 1;
    }

    if (Cb) {
        __hip_bfloat16* ebh = (__hip_bfloat16*)smem;
        __syncthreads();
        #pragma unroll
        for (int i = 0; i < 4; i++) {
            #pragma unroll
            for (int j = 0; j < 4; j++) {
                int colt = wc * 64 + j * 16 + (l & 15);
                float bv = bias ? bias[bn + colt] : 0.f;
                #pragma unroll
                for (int r = 0; r < 4; r++) {
                    int rowc = wr * 64 + i * 16 + (l >> 4) * 4 + r;
                    float v = acc[i][j][r] + bv;
                    if (relu) v = fmaxf(v, 0.f);
                    ebh[rowc * 136 + colt] = __float2bfloat16(v);
                }
            }
        }
        __syncthreads();
        #pragma unroll
        for (int pass = 0; pass < 8; pass++) {
            int idx = pass * 256 + tid;
            int rowc = idx >> 4, colq = idx & 15;
            *(bf16x8*)&Cb[(size_t)(bm + rowc) * N + bn + colq * 8] =
                *(const bf16x8*)&ebh[rowc * 136 + colq * 8];
        }
    } else {
        float* eb = (float*)smem;
        #pragma unroll
        for (int c = 0; c < 2; c++) {
            __syncthreads();
            if (wr == c) {
                #pragma unroll
                for (int i = 0; i < 4; i++) {
                    #pragma unroll
                    for (int j = 0; j < 4; j++) {
                        int colt = wc * 64 + j * 16 + (l & 15);
                        float bv = bias ? bias[bn + colt] : 0.f;
                        #pragma unroll
                        for (int r = 0; r < 4; r++) {
                            int rowc = i * 16 + (l >> 4) * 4 + r;
                            float v = acc[i][j][r] + bv;
                            if (relu) v = fmaxf(v, 0.f);
                            eb[rowc * 132 + colt] = v;
                        }
                    }
                }
            }
            __syncthreads();
            #pragma unroll
            for (int pass = 0; pass < 8; pass++) {
                int idx = pass * 256 + tid;
                int rowc = idx >> 5, colq = idx & 31;
                *(f32x4*)&Cf[(size_t)(bm + c * 64 + rowc) * N + bn + colq * 4] =
                    *(const f32x4*)&eb[rowc * 132 + colq * 4];
            }
        }
    }
}

// ---------------- MFMA GEMM 128x64 tile (N=768 GEMMs)
__global__ __launch_bounds__(256) void gemm_mfma_n64(const __hip_bfloat16* __restrict__ A,
                                                     const __hip_bfloat16* __restrict__ Bt,
                                                     const float* __restrict__ bias,
                                                     float* __restrict__ Cf,
                                                     int M, int N, int K, int relu) {
    __shared__ __align__(16) char smem[49152];
    int tid = threadIdx.x;
    int l = tid & 63, w = tid >> 6;
    int bm = blockIdx.y * 128, bn = blockIdx.x * 64;

    f32x4 acc[2][4] = {};

    stage_tile_n64(A, Bt, K, 0, bm, bn, w, l, smem, smem + 32768);
    int p = 0;
    for (int k0 = 0; k0 < K; k0 += 64) {
        __syncthreads();
        if (k0 + 64 < K)
            stage_tile_n64(A, Bt, K, k0 + 64, bm, bn, w, l,
                           smem + (p ^ 1) * 16384, smem + 32768 + (p ^ 1) * 8192);
        const char* Ab = smem + p * 16384;
        const char* Bb = smem + 32768 + p * 8192;
        #pragma unroll
        for (int ks = 0; ks < 2; ks++) {
            bf16x8 af[2], bfr[4];
            #pragma unroll
            for (int i = 0; i < 2; i++) {
                int row = w * 32 + i * 16 + (l & 15);
                int cb = (ks * 64 + (l >> 4) * 16) ^ ((row & 7) << 4);
                af[i] = *(const bf16x8*)(Ab + row * 128 + cb);
            }
            #pragma unroll
            for (int j = 0; j < 4; j++) {
                int row = j * 16 + (l & 15);
                int cb = (ks * 64 + (l >> 4) * 16) ^ ((row & 7) << 4);
                bfr[j] = *(const bf16x8*)(Bb + row * 128 + cb);
            }
            #pragma unroll
            for (int i = 0; i < 2; i++)
                #pragma unroll
                for (int j = 0; j < 4; j++)
                    acc[i][j] = __builtin_amdgcn_mfma_f32_16x16x32_bf16(af[i], bfr[j], acc[i][j], 0, 0, 0);
        }
        p ^= 1;
    }

    float* eb = (float*)smem;
    __syncthreads();
    #pragma unroll
    for (int i = 0; i < 2; i++) {
        #pragma unroll
        for (int j = 0; j < 4; j++) {
            int colt = j * 16 + (l & 15);
            float bv = bias ? bias[bn + colt] : 0.f;
            #pragma unroll
            for (int r = 0; r < 4; r++) {
                int rowc = w * 32 + i * 16 + (l >> 4) * 4 + r;
                float v = acc[i][j][r] + bv;
                if (relu) v = fmaxf(v, 0.f);
                eb[rowc * 68 + colt] = v;
            }
        }
    }
    __syncthreads();
    #pragma unroll
    for (int pass = 0; pass < 8; pass++) {
        int idx = pass * 256 + tid;
        int rowc = idx >> 4, colq = idx & 15;
        *(f32x4*)&Cf[(size_t)(bm + rowc) * N + bn + colq * 4] =
            *(const f32x4*)&eb[rowc * 68 + colq * 4];
    }
}

// ---------------- QKV GEMM 128x64 tile; bn spans ONE head.
__global__ __launch_bounds__(256) void gemm_qkv_n64(const __hip_bfloat16* __restrict__ A,
                                                    const __hip_bfloat16* __restrict__ kT,
                                                    const __hip_bfloat16* __restrict__ qT,
                                                    const __hip_bfloat16* __restrict__ vT,
                                                    __hip_bfloat16* __restrict__ ko,
                                                    __hip_bfloat16* __restrict__ qo,
                                                    __hip_bfloat16* __restrict__ vto) {
    const __hip_bfloat16* Bt = (blockIdx.z == 0) ? kT : (blockIdx.z == 1) ? qT : vT;
    __shared__ __align__(16) char smem[49152];
    int tid = threadIdx.x;
    int l = tid & 63, w = tid >> 6;
    int bm = blockIdx.y * 128, bn = blockIdx.x * 64;

    f32x4 acc[2][4] = {};

    stage_tile_n64(A, Bt, CC, 0, bm, bn, w, l, smem, smem + 32768);
    int p = 0;
    for (int k0 = 0; k0 < CC; k0 += 64) {
        __syncthreads();
        if (k0 + 64 < CC)
            stage_tile_n64(A, Bt, CC, k0 + 64, bm, bn, w, l,
                           smem + (p ^ 1) * 16384, smem + 32768 + (p ^ 1) * 8192);
        const char* Ab = smem + p * 16384;
        const char* Bb = smem + 32768 + p * 8192;
        #pragma unroll
        for (int ks = 0; ks < 2; ks++) {
            bf16x8 af[2], bfr[4];
            #pragma unroll
            for (int i = 0; i < 2; i++) {
                int row = w * 32 + i * 16 + (l & 15);
                int cb = (ks * 64 + (l >> 4) * 16) ^ ((row & 7) << 4);
                af[i] = *(const bf16x8*)(Ab + row * 128 + cb);
            }
            #pragma unroll
            for (int j = 0; j < 4; j++) {
                int row = j * 16 + (l & 15);
                int cb = (ks * 64 + (l >> 4) * 16) ^ ((row & 7) << 4);
                bfr[j] = *(const bf16x8*)(Bb + row * 128 + cb);
            }
            #pragma unroll
            for (int i = 0; i < 2; i++)
                #pragma unroll
                for (int j = 0; j < 4; j++)
                    acc[i][j] = __builtin_amdgcn_mfma_f32_16x16x32_bf16(af[i], bfr[j], acc[i][j], 0, 0, 0);
        }
        p ^= 1;
    }

    int zz = blockIdx.z;
    int b = bm >> 10, tbase = bm & 1023, head = bn >> 6;
    __hip_bfloat16* eb = (__hip_bfloat16*)smem;
    __syncthreads();
    if (zz != 2) {
        #pragma unroll
        for (int i = 0; i < 2; i++)
            #pragma unroll
            for (int j = 0; j < 4; j++) {
                int colt = j * 16 + (l & 15);
                #pragma unroll
                for (int r = 0; r < 4; r++) {
                    int rowc = w * 32 + i * 16 + (l >> 4) * 4 + r;
                    eb[rowc * 72 + colt] = __float2bfloat16(acc[i][j][r]);
                }
            }
        __syncthreads();
        __hip_bfloat16* O = (zz == 0) ? ko : qo;
        #pragma unroll
        for (int pass = 0; pass < 4; pass++) {
            int idx = pass * 256 + tid;
            int rowc = idx >> 3, colq = idx & 7;
            *(bf16x8*)&O[(((size_t)(b * HH + head)) * TT + tbase + rowc) * DD + colq * 8] =
                *(const bf16x8*)&eb[rowc * 72 + colq * 8];
        }
    } else {
        #pragma unroll
        for (int i = 0; i < 2; i++)
            #pragma unroll
            for (int j = 0; j < 4; j++) {
                int colt = j * 16 + (l & 15);
                #pragma unroll
                for (int r = 0; r < 4; r++) {
                    int rowc = w * 32 + i * 16 + (l >> 4) * 4 + r;
                    eb[colt * 136 + rowc] = __float2bfloat16(acc[i][j][r]);
                }
            }
        __syncthreads();
        #pragma unroll
        for (int pass = 0; pass < 4; pass++) {
            int idx = pass * 256 + tid;
            int line = idx >> 4, tq = idx & 15;
            *(bf16x8*)&vto[(((size_t)(b * HH + head)) * DD + line) * TT + tbase + tq * 8] =
                *(const bf16x8*)&eb[line * 136 + tq * 8];
        }
    }
}

// ---------------- LM head: 256x256, 8 waves, 8-phase counted-vmcnt pipeline (T3+T4+T5),
// nontemporal logits stores (write-once; keep L2 for B-panel).
__global__ __launch_bounds__(512) void lm_head_mfma256(const __hip_bfloat16* __restrict__ A,
                                                       const __hip_bfloat16* __restrict__ Bt,
                                                       const float* __restrict__ bias,
                                                       float* __restrict__ Cf,
                                                       float* __restrict__ pm,
                                                       float* __restrict__ ps) {
    __shared__ __align__(16) char smem[131072];
    int tid = threadIdx.x;
    int l = tid & 63, w = tid >> 6;
    int wr = w >> 2, wc = w & 3;
    int bm = blockIdx.x * 256, bn = blockIdx.y * 256;

    f32x4 acc[8][4] = {};
    const int NT = CC / 64;

    stage_half(A,  CC, 0,  bm,       smem + 0,                 w, l);
    stage_half(A,  CC, 0,  bm + 128, smem + 16384,             w, l);
    stage_half(Bt, CC, 0,  bn,       smem + 65536,             w, l);
    stage_half(Bt, CC, 0,  bn + 128, smem + 65536 + 16384,     w, l);
    stage_half(Bt, CC, 64, bn,       smem + 65536 + 32768,     w, l);
    stage_half(Bt, CC, 64, bn + 128, smem + 65536 + 49152,     w, l);
    asm volatile("s_waitcnt vmcnt(4)\ns_barrier" ::: "memory");

    for (int kt = 0; kt < NT; kt++) {
        int db = kt & 1;
        const char* Ab = smem + db * 32768 + wr * 16384;
        const char* Bb = smem + 65536 + db * 32768;

        bf16x8 bfr[4][2];
        #pragma unroll
        for (int j = 0; j < 4; j++)
            #pragma unroll
            for (int ks = 0; ks < 2; ks++) {
                int RB = wc * 64 + j * 16 + (l & 15);
                int rB = RB & 127;
                int cb = (ks * 64 + (l >> 4) * 16) ^ ((rB & 7) << 4);
                bfr[j][ks] = *(const bf16x8*)(Bb + (RB >> 7) * 16384 + rB * 128 + cb);
            }

        #pragma unroll
        for (int q = 0; q < 4; q++) {
            bf16x8 af[2][2];
            #pragma unroll
            for (int ii = 0; ii < 2; ii++)
                #pragma unroll
                for (int ks = 0; ks < 2; ks++) {
                    int r = (2 * q + ii) * 16 + (l & 15);
                    int cb = (ks * 64 + (l >> 4) * 16) ^ ((r & 7) << 4);
                    af[ii][ks] = *(const bf16x8*)(Ab + r * 128 + cb);
                }
            if (q == 0 && kt + 1 < NT)
                stage_half(A, CC, (kt + 1) * 64, bm,
                           smem + ((kt + 1) & 1) * 32768, w, l);
            if (q == 1 && kt + 1 < NT)
                stage_half(A, CC, (kt + 1) * 64, bm + 128,
                           smem + ((kt + 1) & 1) * 32768 + 16384, w, l);
            if (q == 2 && kt + 2 < NT)
                stage_half(Bt, CC, (kt + 2) * 64, bn,
                           smem + 65536 + db * 32768, w, l);
            if (q == 3 && kt + 2 < NT)
                stage_half(Bt, CC, (kt + 2) * 64, bn + 128,
                           smem + 65536 + db * 32768 + 16384, w, l);

            asm volatile("s_barrier" ::: "memory");
            __builtin_amdgcn_s_setprio(1);
            #pragma unroll
            for (int ks = 0; ks < 2; ks++)
                #pragma unroll
                for (int ii = 0; ii < 2; ii++)
                    #pragma unroll
                    for (int j = 0; j < 4; j++)
                        acc[2 * q + ii][j] = __builtin_amdgcn_mfma_f32_16x16x32_bf16(
                            af[ii][ks], bfr[j][ks], acc[2 * q + ii][j], 0, 0, 0);
            __builtin_amdgcn_s_setprio(0);
            if (q < 3) asm volatile("s_barrier" ::: "memory");
        }
        if (kt == NT - 2)      asm volatile("s_waitcnt vmcnt(0)\ns_barrier" ::: "memory");
        else if (kt < NT - 1)  asm volatile("s_waitcnt vmcnt(4)\ns_barrier" ::: "memory");
    }
    __syncthreads();

    #pragma unroll
    for (int j = 0; j < 4; j++) {
        int col = bn + wc * 64 + j * 16 + (l & 15);
        float bv = (col < VV) ? bias[col] : 0.f;
        #pragma unroll
        for (int i = 0; i < 8; i++)
            #pragma unroll
            for (int r = 0; r < 4; r++)
                acc[i][j][r] += bv;
    }

    int pidx = blockIdx.y * 4 + wc;
    #pragma unroll
    for (int i = 0; i < 8; i++) {
        int row = bm + wr * 128 + i * 16 + (l >> 4) * 4;
        #pragma unroll
        for (int r = 0; r < 4; r++) {
            float pv[4];
            float rmax = -1e30f;
            #pragma unroll
            for (int j = 0; j < 4; j++) {
                int col = bn + wc * 64 + j * 16 + (l & 15);
                float v = (col < VV) ? acc[i][j][r] : -1e30f;
                pv[j] = v;
                rmax = fmaxf(rmax, v);
            }
            #pragma unroll
            for (int msk = 1; msk < 16; msk <<= 1)
                rmax = fmaxf(rmax, __shfl_xor(rmax, msk));
            float s = 0.f;
            #pragma unroll
            for (int j = 0; j < 4; j++) s += __expf(pv[j] - rmax);
            #pragma unroll
            for (int msk = 1; msk < 16; msk <<= 1)
                s += __shfl_xor(s, msk);
            if ((l & 15) == 0) {
                pm[(size_t)(row + r) * NPART + pidx] = rmax;
                ps[(size_t)(row + r) * NPART + pidx] = s;
            }
        }
    }

    // barrier-free per-wave staged epilogue; nontemporal logits stores
    float* eb0 = (float*)smem + (size_t)(w * 2 + 0) * (16 * 68);
    float* eb1 = (float*)smem + (size_t)(w * 2 + 1) * (16 * 68);
    int colg = bn + wc * 64 + l;
    bool valid = colg < VV;
    #pragma unroll
    for (int i = 0; i < 8; i++) {
        float* eb = (i & 1) ? eb1 : eb0;
        #pragma unroll
        for (int j = 0; j < 4; j++) {
            int colt = j * 16 + (l & 15);
            #pragma unroll
            for (int r = 0; r < 4; r++) {
                int rowc = (l >> 4) * 4 + r;
                eb[rowc * 68 + colt] = acc[i][j][r];
            }
        }
        int rowbase = bm + wr * 128 + i * 16;
        #pragma unroll
        for (int pp = 0; pp < 16; pp++) {
            float v = eb[pp * 68 + l];
            if (valid)
                __builtin_nontemporal_store(v, &Cf[(size_t)(rowbase + pp) * VV + colg]);
        }
    }
}

// ---------------- combine LSE partials -> per-row NLL
__global__ __launch_bounds__(256) void nll_combine(const float* __restrict__ pm,
                                                   const float* __restrict__ ps,
                                                   const float* __restrict__ logits,
                                                   const int* __restrict__ y,
                                                   float* __restrict__ rl) {
    int m = blockIdx.x, tid = threadIdx.x;
    __shared__ float rm[256], rs[256];
    float mt = -1e30f, st = 0.f;
    for (int i = tid; i < NPART; i += 256) {
        float mi = pm[(size_t)m * NPART + i];
        float si = ps[(size_t)m * NPART + i];
        float mn = fmaxf(mt, mi);
        st = st * __expf(mt - mn) + si * __expf(mi - mn);
        mt = mn;
    }
    rm[tid] = mt; rs[tid] = st; __syncthreads();
    for (int off = 128; off > 0; off >>= 1) {
        if (tid < off) {
            float ma = rm[tid], mb = rm[tid + off];
            float mn = fmaxf(ma, mb);
            rs[tid] = rs[tid] * __expf(ma - mn) + rs[tid + off] * __expf(mb - mn);
            rm[tid] = mn;
        }
        __syncthreads();
    }
    if (tid == 0)
        rl[m] = logf(rs[0]) + rm[0] - logits[(size_t)m * VV + y[m]];
}

// ---------------- MFMA flash attention (quirk: k plays query role)
// Reversed block order: heavy (large t0) causal blocks dispatch first (LPT).
__global__ __launch_bounds__(256) void attn_mfma(const __hip_bfloat16* __restrict__ kq,
                                                 const __hip_bfloat16* __restrict__ qk,
                                                 const __hip_bfloat16* __restrict__ vt,
                                                 __hip_bfloat16* __restrict__ oc) {
    __shared__ __hip_bfloat16 Qs[2][KVBLK * 64];
    __shared__ __hip_bfloat16 Vs[2][64 * KVBLK];
    __shared__ __hip_bfloat16 Ps[QBLK * KVBLK];
    int tid = threadIdx.x;
    int l = tid & 63, w = tid >> 6;
    int t0 = (int)(gridDim.x - 1 - blockIdx.x) * QBLK;
    size_t bh = (size_t)(blockIdx.z * HH + blockIdx.y);
    const __hip_bfloat16* kqp = kq + bh * TT * DD;
    const __hip_bfloat16* qkp = qk + bh * TT * DD;
    const __hip_bfloat16* vtp = vt + bh * DD * TT;

    bf16x8 af[2][2];
    #pragma unroll
    for (int i = 0; i < 2; i++)
        #pragma unroll
        for (int ks = 0; ks < 2; ks++)
            af[i][ks] = *(const bf16x8*)&kqp[(size_t)(t0 + w * 32 + i * 16 + (l & 15)) * DD
                                             + ks * 32 + (l >> 4) * 8];

    f32x4 acc_o[2][4] = {};
    float mrow[2][4], lrow[2][4];
    #pragma unroll
    for (int i = 0; i < 2; i++)
        #pragma unroll
        for (int r = 0; r < 4; r++) { mrow[i][r] = -1e30f; lrow[i][r] = 0.f; }

    auto stageKV = [&](int pp, int s0) {
        #pragma unroll
        for (int it = 0; it < 2; it++) {
            int chunk = w * 2 + it;
            int o = chunk * 1024 + l * 16;
            int row = o >> 7;
            int cb = (o & 127) ^ ((row & 7) << 4);
            gload_lds16(qkp + (size_t)(s0 + row) * DD + (cb >> 1),
                        (char*)Qs[pp] + chunk * 1024);
            gload_lds16(vtp + (size_t)row * TT + s0 + (cb >> 1),
                        (char*)Vs[pp] + chunk * 1024);
        }
    };

    int nt = (t0 + QBLK) / KVBLK;
    stageKV(0, 0);
    int p = 0;
    for (int ti = 0; ti < nt; ti++) {
        int s0 = ti * KVBLK;
        __syncthreads();
        if (ti + 1 < nt) stageKV(p ^ 1, s0 + KVBLK);

        f32x4 sa[2][4] = {};
        #pragma unroll
        for (int ks = 0; ks < 2; ks++) {
            bf16x8 bfr[4];
            #pragma unroll
            for (int j = 0; j < 4; j++) {
                int row = j * 16 + (l & 15);
                int cb = (ks * 64 + (l >> 4) * 16) ^ ((row & 7) << 4);
                bfr[j] = *(const bf16x8*)((const char*)Qs[p] + row * 128 + cb);
            }
            #pragma unroll
            for (int i = 0; i < 2; i++)
                #pragma unroll
                for (int j = 0; j < 4; j++)
                    sa[i][j] = __builtin_amdgcn_mfma_f32_16x16x32_bf16(af[i][ks], bfr[j], sa[i][j], 0, 0, 0);
        }

        #pragma unroll
        for (int i = 0; i < 2; i++) {
            #pragma unroll
            for (int r = 0; r < 4; r++) {
                int t = t0 + w * 32 + i * 16 + (l >> 4) * 4 + r;
                float pv[4];
                float rmax = -1e30f;
                #pragma unroll
                for (int j = 0; j < 4; j++) {
                    int s = s0 + j * 16 + (l & 15);
                    float v = sa[i][j][r] * 0.125f;
                    v = (s <= t) ? v : -1e30f;
                    pv[j] = v;
                    rmax = fmaxf(rmax, v);
                }
                #pragma unroll
                for (int msk = 1; msk < 16; msk <<= 1)
                    rmax = fmaxf(rmax, __shfl_xor(rmax, msk));
                float mo = mrow[i][r];
                float mn = fmaxf(mo, rmax);
                float fac = __expf(mo - mn);
                float ls = 0.f;
                int prow = w * 32 + i * 16 + (l >> 4) * 4 + r;
                #pragma unroll
                for (int j = 0; j < 4; j++) {
                    float e = __expf(pv[j] - mn);
                    ls += e;
                    int cb = (j * 32 + (l & 15) * 2) ^ ((prow & 7) << 4);
                    *(__hip_bfloat16*)((char*)Ps + prow * 128 + cb) = __float2bfloat16(e);
                }
                #pragma unroll
                for (int msk = 1; msk < 16; msk <<= 1)
                    ls += __shfl_xor(ls, msk);
                mrow[i][r] = mn;
                lrow[i][r] = lrow[i][r] * fac + ls;
                #pragma unroll
                for (int jd = 0; jd < 4; jd++)
                    acc_o[i][jd][r] *= fac;
            }
        }

        #pragma unroll
        for (int ks = 0; ks < 2; ks++) {
            bf16x8 pa[2], vf[4];
            #pragma unroll
            for (int i = 0; i < 2; i++) {
                int row = w * 32 + i * 16 + (l & 15);
                int cb = (ks * 64 + (l >> 4) * 16) ^ ((row & 7) << 4);
                pa[i] = *(const bf16x8*)((const char*)Ps + row * 128 + cb);
            }
            #pragma unroll
            for (int jd = 0; jd < 4; jd++) {
                int row = jd * 16 + (l & 15);
                int cb = (ks * 64 + (l >> 4) * 16) ^ ((row & 7) << 4);
                vf[jd] = *(const bf16x8*)((const char*)Vs[p] + row * 128 + cb);
            }
            #pragma unroll
            for (int i = 0; i < 2; i++)
                #pragma unroll
                for (int jd = 0; jd < 4; jd++)
                    acc_o[i][jd] = __builtin_amdgcn_mfma_f32_16x16x32_bf16(pa[i], vf[jd], acc_o[i][jd], 0, 0, 0);
        }
        p ^= 1;
    }

    int b = blockIdx.z, hh = blockIdx.y;
    #pragma unroll
    for (int i = 0; i < 2; i++) {
        #pragma unroll
        for (int r = 0; r < 4; r++) {
            float inv = 1.f / lrow[i][r];
            int t = t0 + w * 32 + i * 16 + (l >> 4) * 4 + r;
            #pragma unroll
            for (int jd = 0; jd < 4; jd++) {
                int d = jd * 16 + (l & 15);
                oc[((size_t)(b * TT + t)) * CC + hh * DD + d] =
                    __float2bfloat16(acc_o[i][jd][r] * inv);
            }
        }
    }
}

// ---------------- hb = bf16(LN(bf16(hb) + t)) — wave-reduce version (2 barriers)
__global__ __launch_bounds__(256) void resid_ln(__hip_bfloat16* __restrict__ hb,
                                                const float* __restrict__ t,
                                                const float* __restrict__ g,
                                                const float* __restrict__ bta) {
    int row = blockIdx.x;
    int tid = threadIdx.x;
    int l = tid & 63, w = tid >> 6;
    __shared__ float pa[4], pb[4];
    float x[3];
    float s = 0.f;
    #pragma unroll
    for (int i = 0; i < 3; i++) {
        int c = tid + i * 256;
        x[i] = __bfloat162float(hb[(size_t)row * CC + c]) + t[(size_t)row * CC + c];
        s += x[i];
    }
    #pragma unroll
    for (int msk = 1; msk < 64; msk <<= 1) s += __shfl_xor(s, msk);
    if (l == 0) pa[w] = s;
    __syncthreads();
    float mean = (pa[0] + pa[1] + pa[2] + pa[3]) * (1.f / CC);
    float s2 = 0.f;
    #pragma unroll
    for (int i = 0; i < 3; i++) { float dd = x[i] - mean; s2 += dd * dd; }
    #pragma unroll
    for (int msk = 1; msk < 64; msk <<= 1) s2 += __shfl_xor(s2, msk);
    if (l == 0) pb[w] = s2;
    __syncthreads();
    float inv = rsqrtf((pb[0] + pb[1] + pb[2] + pb[3]) * (1.f / CC) + 1e-5f);
    #pragma unroll
    for (int i = 0; i < 3; i++) {
        int c = tid + i * 256;
        hb[(size_t)row * CC + c] = __float2bfloat16((x[i] - mean) * inv * g[c] + bta[c]);
    }
}

__global__ __launch_bounds__(256) void loss_reduce(const float* __restrict__ rl,
                                                   float* __restrict__ out) {
    int tid = threadIdx.x;
    __shared__ float red[256];
    float s = 0.f;
    for (int i = tid; i < MROWS; i += 256) s += rl[i];
    red[tid] = s; __syncthreads();
    for (int off = 128; off > 0; off >>= 1) {
        if (tid < off) red[tid] += red[tid + off];
        __syncthreads();
    }
    if (tid == 0) out[0] = red[0] * (1.f / MROWS);
}

extern "C" void kernel_launch(void* const* d_in, const int* in_sizes, int n_in,
                              void* d_out, int out_size, void* d_ws, size_t ws_size,
                              hipStream_t stream) {
    const int*   x     = (const int*)d_in[0];
    const int*   y     = (const int*)d_in[1];
    const float* tok   = (const float*)d_in[2];
    const float* pos   = (const float*)d_in[3];
    const float* Wk    = (const float*)d_in[4];
    const float* Wq    = (const float*)d_in[5];
    const float* Wv    = (const float*)d_in[6];
    const float* Wproj = (const float*)d_in[7];
    const float* bproj = (const float*)d_in[8];
    const float* ln1g  = (const float*)d_in[9];
    const float* ln1b  = (const float*)d_in[10];
    const float* W1    = (const float*)d_in[11];
    const float* b1    = (const float*)d_in[12];
    const float* W2    = (const float*)d_in[13];
    const float* b2    = (const float*)d_in[14];
    const float* ln2g  = (const float*)d_in[15];
    const float* ln2b  = (const float*)d_in[16];
    const float* Wlm   = (const float*)d_in[17];
    const float* blm   = (const float*)d_in[18];

    float* logits = (float*)d_out;
    float* lossp  = (float*)d_out + ((size_t)out_size - 1);

    char* p = (char*)d_ws;
    auto alloc = [&](size_t bytes) { char* r = p; p += (bytes + 255) & ~255ULL; return r; };
    const size_t S_HC = (size_t)MROWS * CC;

    float* tmpf = (float*)alloc(S_HC * 4);
    float* rl   = (float*)alloc(MROWS * 4);
    float* pm   = (float*)alloc((size_t)MROWS * NPART * 4);
    float* ps   = (float*)alloc((size_t)MROWS * NPART * 4);
    __hip_bfloat16* kbb  = (__hip_bfloat16*)alloc(S_HC * 2);
    __hip_bfloat16* qbb  = (__hip_bfloat16*)alloc(S_HC * 2);
    __hip_bfloat16* vtb  = (__hip_bfloat16*)alloc(S_HC * 2);
    __hip_bfloat16* hb   = (__hip_bfloat16*)alloc(S_HC * 2);
    __hip_bfloat16* ocb  = (__hip_bfloat16*)alloc(S_HC * 2);
    __hip_bfloat16* ff1b = (__hip_bfloat16*)alloc((size_t)MROWS * FFH * 2);
    __hip_bfloat16* kT   = (__hip_bfloat16*)alloc((size_t)LL * CC * CC * 2);
    __hip_bfloat16* qT   = (__hip_bfloat16*)alloc((size_t)LL * CC * CC * 2);
    __hip_bfloat16* vT   = (__hip_bfloat16*)alloc((size_t)LL * CC * CC * 2);
    __hip_bfloat16* pT   = (__hip_bfloat16*)alloc((size_t)LL * CC * CC * 2);
    __hip_bfloat16* w1T  = (__hip_bfloat16*)alloc((size_t)LL * CC * FFH * 2);
    __hip_bfloat16* w2T  = (__hip_bfloat16*)alloc((size_t)LL * FFH * CC * 2);
    __hip_bfloat16* lmT  = (__hip_bfloat16*)alloc((size_t)VPAD2 * CC * 2);

    dim3 blk(256);

    cvtT_qkv<<<dim3(24, 2, 3 * 144), blk, 0, stream>>>(Wk, Wq, Wv, kT, qT, vT);
    cvtT_mat<<<dim3(24, 24, LL), blk, 0, stream>>>(Wproj, pT, CC, CC,
                                                   (size_t)CC * CC, (size_t)CC * CC);
    cvtT_mat<<<dim3(96, 24, LL), blk, 0, stream>>>(W1, w1T, CC, FFH,
                                                   (size_t)CC * FFH, (size_t)FFH * CC);
    cvtT_mat<<<dim3(24, 96, LL), blk, 0, stream>>>(W2, w2T, FFH, CC,
                                                   (size_t)FFH * CC, (size_t)CC * FFH);
    cvtT_mat<<<dim3(VPAD2 / 32, 24, 1), blk, 0, stream>>>(Wlm, lmT, CC, VV, 0, 0);

    embed_kernel<<<dim3((MROWS * CC + 255) / 256), blk, 0, stream>>>(x, tok, pos, hb);

    for (int l = 0; l < LL; l++) {
        const __hip_bfloat16* kT_l = kT + (size_t)l * CC * CC;
        const __hip_bfloat16* qT_l = qT + (size_t)l * CC * CC;
        const __hip_bfloat16* vT_l = vT + (size_t)l * CC * CC;
        const __hip_bfloat16* pT_l = pT + (size_t)l * CC * CC;
        const __hip_bfloat16* w1T_l = w1T + (size_t)l * CC * FFH;
        const __hip_bfloat16* w2T_l = w2T + (size_t)l * FFH * CC;

        gemm_qkv_n64<<<dim3(CC / 64, MROWS / 128, 3), blk, 0, stream>>>(
            hb, kT_l, qT_l, vT_l, kbb, qbb, vtb);
        attn_mfma<<<dim3(TT / QBLK, HH, BB), blk, 0, stream>>>(kbb, qbb, vtb, ocb);
        gemm_mfma_n64<<<dim3(CC / 64, MROWS / 128), blk, 0, stream>>>(
            ocb, pT_l, bproj + (size_t)l * CC, tmpf, MROWS, CC, CC, 0);
        resid_ln<<<dim3(MROWS), blk, 0, stream>>>(hb, tmpf, ln1g + (size_t)l * CC,
                                                  ln1b + (size_t)l * CC);
        gemm_mfma<<<dim3(FFH / 128, MROWS / 128), blk, 0, stream>>>(
            hb, w1T_l, b1 + (size_t)l * FFH, (float*)nullptr, ff1b,
            MROWS, FFH, CC, 1);
        gemm_mfma_n64<<<dim3(CC / 64, MROWS / 128), blk, 0, stream>>>(
            ff1b, w2T_l, b2 + (size_t)l * CC, tmpf, MROWS, CC, FFH, 0);
        resid_ln<<<dim3(MROWS), blk, 0, stream>>>(hb, tmpf, ln2g + (size_t)l * CC,
                                                  ln2b + (size_t)l * CC);
    }

    lm_head_mfma256<<<dim3(MROWS / 256, VPAD2 / 256), dim3(512), 0, stream>>>(
        hb, lmT, blm, logits, pm, ps);
    nll_combine<<<dim3(MROWS), blk, 0, stream>>>(pm, ps, logits, y, rl);
    loss_reduce<<<dim3(1), blk, 0, stream>>>(rl, lossp);
}

// Round 15
// 3106.552 us; speedup vs baseline: 1.0153x; 1.0153x over previous
//
#include <hip/hip_runtime.h>
#include <hip/hip_bf16.h>
#include <math.h>

#define BB 4
#define TT 1024
#define VV 50257
#define VPAD2 50432
#define CC 768
#define HH 12
#define DD 64
#define LL 12
#define FFH 3072
#define MROWS (BB*TT)   // 4096
#define QBLK 128
#define KVBLK 64
#define NPART (VPAD2 / 64)        // 788 partials per row

typedef __bf16 bf16x8 __attribute__((ext_vector_type(8)));
typedef float  f32x4  __attribute__((ext_vector_type(4)));
typedef unsigned int u32;
#define AS1 __attribute__((address_space(1)))
#define AS3 __attribute__((address_space(3)))

static __device__ __forceinline__ void gload_lds16(const void* g, void* l) {
    __builtin_amdgcn_global_load_lds((const AS1 u32*)g, (AS3 u32*)l, 16, 0, 0);
}

// stage one 128x64 bf16 tile pair into linear LDS, source pre-swizzled (4 waves)
static __device__ __forceinline__ void stage_tile(const __hip_bfloat16* __restrict__ A,
                                                  const __hip_bfloat16* __restrict__ Bt,
                                                  int Kld, int k0, int bm, int bn,
                                                  int w, int l, char* As, char* Bs) {
    #pragma unroll
    for (int it = 0; it < 4; it++) {
        int chunk = w * 4 + it;
        int o = chunk * 1024 + l * 16;
        int row = o >> 7;
        int cb = (o & 127) ^ ((row & 7) << 4);
        gload_lds16(A + (size_t)(bm + row) * Kld + k0 + (cb >> 1), As + chunk * 1024);
        gload_lds16(Bt + (size_t)(bn + row) * Kld + k0 + (cb >> 1), Bs + chunk * 1024);
    }
}

// stage A(128x64) + B(64x64) for the n64 tile (4 waves)
static __device__ __forceinline__ void stage_tile_n64(const __hip_bfloat16* __restrict__ A,
                                                      const __hip_bfloat16* __restrict__ Bt,
                                                      int Kld, int k0, int bm, int bn,
                                                      int w, int l, char* As, char* Bs) {
    #pragma unroll
    for (int it = 0; it < 4; it++) {
        int chunk = w * 4 + it;
        int o = chunk * 1024 + l * 16;
        int row = o >> 7;
        int cb = (o & 127) ^ ((row & 7) << 4);
        gload_lds16(A + (size_t)(bm + row) * Kld + k0 + (cb >> 1), As + chunk * 1024);
    }
    #pragma unroll
    for (int it = 0; it < 2; it++) {
        int chunk = w * 2 + it;
        int o = chunk * 1024 + l * 16;
        int row = o >> 7;
        int cb = (o & 127) ^ ((row & 7) << 4);
        gload_lds16(Bt + (size_t)(bn + row) * Kld + k0 + (cb >> 1), Bs + chunk * 1024);
    }
}

// stage one 128-row x 64-col half-tile of ONE tensor (16KB; 512 threads x 2 loads)
static __device__ __forceinline__ void stage_half(const __hip_bfloat16* __restrict__ src,
                                                  int Kld, int k0, int rowbase,
                                                  char* dst, int w, int l) {
    #pragma unroll
    for (int it = 0; it < 2; it++) {
        int chunk = w * 2 + it;
        int o = chunk * 1024 + l * 16;
        int row = o >> 7;
        int cb = (o & 127) ^ ((row & 7) << 4);
        gload_lds16(src + (size_t)(rowbase + row) * Kld + k0 + (cb >> 1), dst + chunk * 1024);
    }
}

// ---------------- embedding (bf16 residual stream)
__global__ void embed_kernel(const int* __restrict__ x, const float* __restrict__ tok,
                             const float* __restrict__ pos,
                             __hip_bfloat16* __restrict__ hb) {
    int idx = blockIdx.x * 256 + threadIdx.x;
    if (idx >= MROWS * CC) return;
    int row = idx / CC, c = idx - row * CC;
    int id = x[row];
    hb[idx] = __float2bfloat16(tok[(size_t)id * CC + c] + pos[(size_t)id * CC + c]);
}

// ---------------- convert + transpose weights
__global__ __launch_bounds__(256) void cvtT_mat(const float* __restrict__ in,
                                                __hip_bfloat16* __restrict__ out,
                                                int K, int Nin,
                                                size_t ibs, size_t obs) {
    __shared__ float t[32][33];
    const float* ip = in + blockIdx.z * ibs;
    __hip_bfloat16* op = out + blockIdx.z * obs;
    int n0 = blockIdx.x * 32, k0 = blockIdx.y * 32;
    int tx = threadIdx.x & 31, ty = threadIdx.x >> 5;
    #pragma unroll
    for (int i = 0; i < 4; i++) {
        int k = k0 + ty + i * 8, n = n0 + tx;
        t[ty + i * 8][tx] = (n < Nin) ? ip[(size_t)k * Nin + n] : 0.f;
    }
    __syncthreads();
    #pragma unroll
    for (int i = 0; i < 4; i++) {
        int n = n0 + ty + i * 8, k = k0 + tx;
        op[(size_t)n * K + k] = __float2bfloat16(t[tx][ty + i * 8]);
    }
}

__global__ __launch_bounds__(256) void cvtT_qkv(const float* __restrict__ Wk,
                                                const float* __restrict__ Wq,
                                                const float* __restrict__ Wv,
                                                __hip_bfloat16* __restrict__ kT,
                                                __hip_bfloat16* __restrict__ qT,
                                                __hip_bfloat16* __restrict__ vT) {
    int z = blockIdx.z;
    int tensor = z / 144, lh = z % 144;
    int l = lh / HH, hh = lh % HH;
    const float* in = (tensor == 0 ? Wk : tensor == 1 ? Wq : Wv) + (size_t)lh * CC * DD;
    __hip_bfloat16* out = (tensor == 0 ? kT : tensor == 1 ? qT : vT)
                          + ((size_t)l * CC + hh * DD) * CC;
    __shared__ float t[32][33];
    int c0 = blockIdx.x * 32, d0 = blockIdx.y * 32;
    int tx = threadIdx.x & 31, ty = threadIdx.x >> 5;
    #pragma unroll
    for (int i = 0; i < 4; i++)
        t[ty + i * 8][tx] = in[(size_t)(c0 + ty + i * 8) * DD + d0 + tx];
    __syncthreads();
    #pragma unroll
    for (int i = 0; i < 4; i++)
        out[(size_t)(d0 + ty + i * 8) * CC + c0 + tx] = __float2bfloat16(t[tx][ty + i * 8]);
}

// ---------------- MFMA GEMM 128x128 dbuf + LDS-staged coalesced epilogue.
__global__ __launch_bounds__(256) void gemm_mfma(const __hip_bfloat16* __restrict__ A,
                                                 const __hip_bfloat16* __restrict__ Bt,
                                                 const float* __restrict__ bias,
                                                 float* __restrict__ Cf,
                                                 __hip_bfloat16* __restrict__ Cb,
                                                 int M, int N, int K, int relu) {
    __shared__ __align__(16) char smem[65536];
    int tid = threadIdx.x;
    int l = tid & 63, w = tid >> 6;
    int wr = w >> 1, wc = w & 1;
    int bm = blockIdx.y * 128, bn = blockIdx.x * 128;

    f32x4 acc[4][4] = {};

    stage_tile(A, Bt, K, 0, bm, bn, w, l, smem, smem + 32768);
    int p = 0;
    for (int k0 = 0; k0 < K; k0 += 64) {
        __syncthreads();
        if (k0 + 64 < K)
            stage_tile(A, Bt, K, k0 + 64, bm, bn, w, l,
                       smem + (p ^ 1) * 16384, smem + 32768 + (p ^ 1) * 16384);
        const char* Ab = smem + p * 16384;
        const char* Bb = smem + 32768 + p * 16384;
        #pragma unroll
        for (int ks = 0; ks < 2; ks++) {
            bf16x8 af[4], bfr[4];
            #pragma unroll
            for (int i = 0; i < 4; i++) {
                int row = wr * 64 + i * 16 + (l & 15);
                int cb = (ks * 64 + (l >> 4) * 16) ^ ((row & 7) << 4);
                af[i] = *(const bf16x8*)(Ab + row * 128 + cb);
            }
            #pragma unroll
            for (int j = 0; j < 4; j++) {
                int row = wc * 64 + j * 16 + (l & 15);
                int cb = (ks * 64 + (l >> 4) * 16) ^ ((row & 7) << 4);
                bfr[j] = *(const bf16x8*)(Bb + row * 128 + cb);
            }
            #pragma unroll
            for (int i = 0; i < 4; i++)
                #pragma unroll
                for (int j = 0; j < 4; j++)
                    acc[i][j] = __builtin_amdgcn_mfma_f32_16x16x32_bf16(af[i], bfr[j], acc[i][j], 0, 0, 0);
        }
        p ^= 1;
    }

    if (Cb) {
        __hip_bfloat16* ebh = (__hip_bfloat16*)smem;
        __syncthreads();
        #pragma unroll
        for (int i = 0; i < 4; i++) {
            #pragma unroll
            for (int j = 0; j < 4; j++) {
                int colt = wc * 64 + j * 16 + (l & 15);
                float bv = bias ? bias[bn + colt] : 0.f;
                #pragma unroll
                for (int r = 0; r < 4; r++) {
                    int rowc = wr * 64 + i * 16 + (l >> 4) * 4 + r;
                    float v = acc[i][j][r] + bv;
                    if (relu) v = fmaxf(v, 0.f);
                    ebh[rowc * 136 + colt] = __float2bfloat16(v);
                }
            }
        }
        __syncthreads();
        #pragma unroll
        for (int pass = 0; pass < 8; pass++) {
            int idx = pass * 256 + tid;
            int rowc = idx >> 4, colq = idx & 15;
            *(bf16x8*)&Cb[(size_t)(bm + rowc) * N + bn + colq * 8] =
                *(const bf16x8*)&ebh[rowc * 136 + colq * 8];
        }
    } else {
        float* eb = (float*)smem;
        #pragma unroll
        for (int c = 0; c < 2; c++) {
            __syncthreads();
            if (wr == c) {
                #pragma unroll
                for (int i = 0; i < 4; i++) {
                    #pragma unroll
                    for (int j = 0; j < 4; j++) {
                        int colt = wc * 64 + j * 16 + (l & 15);
                        float bv = bias ? bias[bn + colt] : 0.f;
                        #pragma unroll
                        for (int r = 0; r < 4; r++) {
                            int rowc = i * 16 + (l >> 4) * 4 + r;
                            float v = acc[i][j][r] + bv;
                            if (relu) v = fmaxf(v, 0.f);
                            eb[rowc * 132 + colt] = v;
                        }
                    }
                }
            }
            __syncthreads();
            #pragma unroll
            for (int pass = 0; pass < 8; pass++) {
                int idx = pass * 256 + tid;
                int rowc = idx >> 5, colq = idx & 31;
                *(f32x4*)&Cf[(size_t)(bm + c * 64 + rowc) * N + bn + colq * 4] =
                    *(const f32x4*)&eb[rowc * 132 + colq * 4];
            }
        }
    }
}

// ---------------- MFMA GEMM 128x64 tile (N=768 GEMMs)
__global__ __launch_bounds__(256) void gemm_mfma_n64(const __hip_bfloat16* __restrict__ A,
                                                     const __hip_bfloat16* __restrict__ Bt,
                                                     const float* __restrict__ bias,
                                                     float* __restrict__ Cf,
                                                     int M, int N, int K, int relu) {
    __shared__ __align__(16) char smem[49152];
    int tid = threadIdx.x;
    int l = tid & 63, w = tid >> 6;
    int bm = blockIdx.y * 128, bn = blockIdx.x * 64;

    f32x4 acc[2][4] = {};

    stage_tile_n64(A, Bt, K, 0, bm, bn, w, l, smem, smem + 32768);
    int p = 0;
    for (int k0 = 0; k0 < K; k0 += 64) {
        __syncthreads();
        if (k0 + 64 < K)
            stage_tile_n64(A, Bt, K, k0 + 64, bm, bn, w, l,
                           smem + (p ^ 1) * 16384, smem + 32768 + (p ^ 1) * 8192);
        const char* Ab = smem + p * 16384;
        const char* Bb = smem + 32768 + p * 8192;
        #pragma unroll
        for (int ks = 0; ks < 2; ks++) {
            bf16x8 af[2], bfr[4];
            #pragma unroll
            for (int i = 0; i < 2; i++) {
                int row = w * 32 + i * 16 + (l & 15);
                int cb = (ks * 64 + (l >> 4) * 16) ^ ((row & 7) << 4);
                af[i] = *(const bf16x8*)(Ab + row * 128 + cb);
            }
            #pragma unroll
            for (int j = 0; j < 4; j++) {
                int row = j * 16 + (l & 15);
                int cb = (ks * 64 + (l >> 4) * 16) ^ ((row & 7) << 4);
                bfr[j] = *(const bf16x8*)(Bb + row * 128 + cb);
            }
            #pragma unroll
            for (int i = 0; i < 2; i++)
                #pragma unroll
                for (int j = 0; j < 4; j++)
                    acc[i][j] = __builtin_amdgcn_mfma_f32_16x16x32_bf16(af[i], bfr[j], acc[i][j], 0, 0, 0);
        }
        p ^= 1;
    }

    float* eb = (float*)smem;
    __syncthreads();
    #pragma unroll
    for (int i = 0; i < 2; i++) {
        #pragma unroll
        for (int j = 0; j < 4; j++) {
            int colt = j * 16 + (l & 15);
            float bv = bias ? bias[bn + colt] : 0.f;
            #pragma unroll
            for (int r = 0; r < 4; r++) {
                int rowc = w * 32 + i * 16 + (l >> 4) * 4 + r;
                float v = acc[i][j][r] + bv;
                if (relu) v = fmaxf(v, 0.f);
                eb[rowc * 68 + colt] = v;
            }
        }
    }
    __syncthreads();
    #pragma unroll
    for (int pass = 0; pass < 8; pass++) {
        int idx = pass * 256 + tid;
        int rowc = idx >> 4, colq = idx & 15;
        *(f32x4*)&Cf[(size_t)(bm + rowc) * N + bn + colq * 4] =
            *(const f32x4*)&eb[rowc * 68 + colq * 4];
    }
}

// ---------------- QKV GEMM 128x64 tile; bn spans ONE head.
__global__ __launch_bounds__(256) void gemm_qkv_n64(const __hip_bfloat16* __restrict__ A,
                                                    const __hip_bfloat16* __restrict__ kT,
                                                    const __hip_bfloat16* __restrict__ qT,
                                                    const __hip_bfloat16* __restrict__ vT,
                                                    __hip_bfloat16* __restrict__ ko,
                                                    __hip_bfloat16* __restrict__ qo,
                                                    __hip_bfloat16* __restrict__ vto) {
    const __hip_bfloat16* Bt = (blockIdx.z == 0) ? kT : (blockIdx.z == 1) ? qT : vT;
    __shared__ __align__(16) char smem[49152];
    int tid = threadIdx.x;
    int l = tid & 63, w = tid >> 6;
    int bm = blockIdx.y * 128, bn = blockIdx.x * 64;

    f32x4 acc[2][4] = {};

    stage_tile_n64(A, Bt, CC, 0, bm, bn, w, l, smem, smem + 32768);
    int p = 0;
    for (int k0 = 0; k0 < CC; k0 += 64) {
        __syncthreads();
        if (k0 + 64 < CC)
            stage_tile_n64(A, Bt, CC, k0 + 64, bm, bn, w, l,
                           smem + (p ^ 1) * 16384, smem + 32768 + (p ^ 1) * 8192);
        const char* Ab = smem + p * 16384;
        const char* Bb = smem + 32768 + p * 8192;
        #pragma unroll
        for (int ks = 0; ks < 2; ks++) {
            bf16x8 af[2], bfr[4];
            #pragma unroll
            for (int i = 0; i < 2; i++) {
                int row = w * 32 + i * 16 + (l & 15);
                int cb = (ks * 64 + (l >> 4) * 16) ^ ((row & 7) << 4);
                af[i] = *(const bf16x8*)(Ab + row * 128 + cb);
            }
            #pragma unroll
            for (int j = 0; j < 4; j++) {
                int row = j * 16 + (l & 15);
                int cb = (ks * 64 + (l >> 4) * 16) ^ ((row & 7) << 4);
                bfr[j] = *(const bf16x8*)(Bb + row * 128 + cb);
            }
            #pragma unroll
            for (int i = 0; i < 2; i++)
                #pragma unroll
                for (int j = 0; j < 4; j++)
                    acc[i][j] = __builtin_amdgcn_mfma_f32_16x16x32_bf16(af[i], bfr[j], acc[i][j], 0, 0, 0);
        }
        p ^= 1;
    }

    int zz = blockIdx.z;
    int b = bm >> 10, tbase = bm & 1023, head = bn >> 6;
    __hip_bfloat16* eb = (__hip_bfloat16*)smem;
    __syncthreads();
    if (zz != 2) {
        #pragma unroll
        for (int i = 0; i < 2; i++)
            #pragma unroll
            for (int j = 0; j < 4; j++) {
                int colt = j * 16 + (l & 15);
                #pragma unroll
                for (int r = 0; r < 4; r++) {
                    int rowc = w * 32 + i * 16 + (l >> 4) * 4 + r;
                    eb[rowc * 72 + colt] = __float2bfloat16(acc[i][j][r]);
                }
            }
        __syncthreads();
        __hip_bfloat16* O = (zz == 0) ? ko : qo;
        #pragma unroll
        for (int pass = 0; pass < 4; pass++) {
            int idx = pass * 256 + tid;
            int rowc = idx >> 3, colq = idx & 7;
            *(bf16x8*)&O[(((size_t)(b * HH + head)) * TT + tbase + rowc) * DD + colq * 8] =
                *(const bf16x8*)&eb[rowc * 72 + colq * 8];
        }
    } else {
        #pragma unroll
        for (int i = 0; i < 2; i++)
            #pragma unroll
            for (int j = 0; j < 4; j++) {
                int colt = j * 16 + (l & 15);
                #pragma unroll
                for (int r = 0; r < 4; r++) {
                    int rowc = w * 32 + i * 16 + (l >> 4) * 4 + r;
                    eb[colt * 136 + rowc] = __float2bfloat16(acc[i][j][r]);
                }
            }
        __syncthreads();
        #pragma unroll
        for (int pass = 0; pass < 4; pass++) {
            int idx = pass * 256 + tid;
            int line = idx >> 4, tq = idx & 15;
            *(bf16x8*)&vto[(((size_t)(b * HH + head)) * DD + line) * TT + tbase + tq * 8] =
                *(const bf16x8*)&eb[line * 136 + tq * 8];
        }
    }
}

// ---------------- LM head: 256x256, 8 waves, 8-phase counted-vmcnt pipeline (T3+T4+T5).
__global__ __launch_bounds__(512) void lm_head_mfma256(const __hip_bfloat16* __restrict__ A,
                                                       const __hip_bfloat16* __restrict__ Bt,
                                                       const float* __restrict__ bias,
                                                       float* __restrict__ Cf,
                                                       float* __restrict__ pm,
                                                       float* __restrict__ ps) {
    __shared__ __align__(16) char smem[131072];
    int tid = threadIdx.x;
    int l = tid & 63, w = tid >> 6;
    int wr = w >> 2, wc = w & 3;
    int bm = blockIdx.x * 256, bn = blockIdx.y * 256;

    f32x4 acc[8][4] = {};
    const int NT = CC / 64;

    stage_half(A,  CC, 0,  bm,       smem + 0,                 w, l);
    stage_half(A,  CC, 0,  bm + 128, smem + 16384,             w, l);
    stage_half(Bt, CC, 0,  bn,       smem + 65536,             w, l);
    stage_half(Bt, CC, 0,  bn + 128, smem + 65536 + 16384,     w, l);
    stage_half(Bt, CC, 64, bn,       smem + 65536 + 32768,     w, l);
    stage_half(Bt, CC, 64, bn + 128, smem + 65536 + 49152,     w, l);
    asm volatile("s_waitcnt vmcnt(4)\ns_barrier" ::: "memory");

    for (int kt = 0; kt < NT; kt++) {
        int db = kt & 1;
        const char* Ab = smem + db * 32768 + wr * 16384;
        const char* Bb = smem + 65536 + db * 32768;

        bf16x8 bfr[4][2];
        #pragma unroll
        for (int j = 0; j < 4; j++)
            #pragma unroll
            for (int ks = 0; ks < 2; ks++) {
                int RB = wc * 64 + j * 16 + (l & 15);
                int rB = RB & 127;
                int cb = (ks * 64 + (l >> 4) * 16) ^ ((rB & 7) << 4);
                bfr[j][ks] = *(const bf16x8*)(Bb + (RB >> 7) * 16384 + rB * 128 + cb);
            }

        #pragma unroll
        for (int q = 0; q < 4; q++) {
            bf16x8 af[2][2];
            #pragma unroll
            for (int ii = 0; ii < 2; ii++)
                #pragma unroll
                for (int ks = 0; ks < 2; ks++) {
                    int r = (2 * q + ii) * 16 + (l & 15);
                    int cb = (ks * 64 + (l >> 4) * 16) ^ ((r & 7) << 4);
                    af[ii][ks] = *(const bf16x8*)(Ab + r * 128 + cb);
                }
            if (q == 0 && kt + 1 < NT)
                stage_half(A, CC, (kt + 1) * 64, bm,
                           smem + ((kt + 1) & 1) * 32768, w, l);
            if (q == 1 && kt + 1 < NT)
                stage_half(A, CC, (kt + 1) * 64, bm + 128,
                           smem + ((kt + 1) & 1) * 32768 + 16384, w, l);
            if (q == 2 && kt + 2 < NT)
                stage_half(Bt, CC, (kt + 2) * 64, bn,
                           smem + 65536 + db * 32768, w, l);
            if (q == 3 && kt + 2 < NT)
                stage_half(Bt, CC, (kt + 2) * 64, bn + 128,
                           smem + 65536 + db * 32768 + 16384, w, l);

            asm volatile("s_barrier" ::: "memory");
            __builtin_amdgcn_s_setprio(1);
            #pragma unroll
            for (int ks = 0; ks < 2; ks++)
                #pragma unroll
                for (int ii = 0; ii < 2; ii++)
                    #pragma unroll
                    for (int j = 0; j < 4; j++)
                        acc[2 * q + ii][j] = __builtin_amdgcn_mfma_f32_16x16x32_bf16(
                            af[ii][ks], bfr[j][ks], acc[2 * q + ii][j], 0, 0, 0);
            __builtin_amdgcn_s_setprio(0);
            if (q < 3) asm volatile("s_barrier" ::: "memory");
        }
        if (kt == NT - 2)      asm volatile("s_waitcnt vmcnt(0)\ns_barrier" ::: "memory");
        else if (kt < NT - 1)  asm volatile("s_waitcnt vmcnt(4)\ns_barrier" ::: "memory");
    }
    __syncthreads();

    #pragma unroll
    for (int j = 0; j < 4; j++) {
        int col = bn + wc * 64 + j * 16 + (l & 15);
        float bv = (col < VV) ? bias[col] : 0.f;
        #pragma unroll
        for (int i = 0; i < 8; i++)
            #pragma unroll
            for (int r = 0; r < 4; r++)
                acc[i][j][r] += bv;
    }

    int pidx = blockIdx.y * 4 + wc;
    #pragma unroll
    for (int i = 0; i < 8; i++) {
        int row = bm + wr * 128 + i * 16 + (l >> 4) * 4;
        #pragma unroll
        for (int r = 0; r < 4; r++) {
            float pv[4];
            float rmax = -1e30f;
            #pragma unroll
            for (int j = 0; j < 4; j++) {
                int col = bn + wc * 64 + j * 16 + (l & 15);
                float v = (col < VV) ? acc[i][j][r] : -1e30f;
                pv[j] = v;
                rmax = fmaxf(rmax, v);
            }
            #pragma unroll
            for (int msk = 1; msk < 16; msk <<= 1)
                rmax = fmaxf(rmax, __shfl_xor(rmax, msk));
            float s = 0.f;
            #pragma unroll
            for (int j = 0; j < 4; j++) s += __expf(pv[j] - rmax);
            #pragma unroll
            for (int msk = 1; msk < 16; msk <<= 1)
                s += __shfl_xor(s, msk);
            if ((l & 15) == 0) {
                pm[(size_t)(row + r) * NPART + pidx] = rmax;
                ps[(size_t)(row + r) * NPART + pidx] = s;
            }
        }
    }

    // barrier-free per-wave staged epilogue (plain stores)
    float* eb0 = (float*)smem + (size_t)(w * 2 + 0) * (16 * 68);
    float* eb1 = (float*)smem + (size_t)(w * 2 + 1) * (16 * 68);
    int colg = bn + wc * 64 + l;
    bool valid = colg < VV;
    #pragma unroll
    for (int i = 0; i < 8; i++) {
        float* eb = (i & 1) ? eb1 : eb0;
        #pragma unroll
        for (int j = 0; j < 4; j++) {
            int colt = j * 16 + (l & 15);
            #pragma unroll
            for (int r = 0; r < 4; r++) {
                int rowc = (l >> 4) * 4 + r;
                eb[rowc * 68 + colt] = acc[i][j][r];
            }
        }
        int rowbase = bm + wr * 128 + i * 16;
        #pragma unroll
        for (int pp = 0; pp < 16; pp++) {
            float v = eb[pp * 68 + l];
            if (valid) Cf[(size_t)(rowbase + pp) * VV + colg] = v;
        }
    }
}

// ---------------- combine LSE partials -> per-row NLL
__global__ __launch_bounds__(256) void nll_combine(const float* __restrict__ pm,
                                                   const float* __restrict__ ps,
                                                   const float* __restrict__ logits,
                                                   const int* __restrict__ y,
                                                   float* __restrict__ rl) {
    int m = blockIdx.x, tid = threadIdx.x;
    __shared__ float rm[256], rs[256];
    float mt = -1e30f, st = 0.f;
    for (int i = tid; i < NPART; i += 256) {
        float mi = pm[(size_t)m * NPART + i];
        float si = ps[(size_t)m * NPART + i];
        float mn = fmaxf(mt, mi);
        st = st * __expf(mt - mn) + si * __expf(mi - mn);
        mt = mn;
    }
    rm[tid] = mt; rs[tid] = st; __syncthreads();
    for (int off = 128; off > 0; off >>= 1) {
        if (tid < off) {
            float ma = rm[tid], mb = rm[tid + off];
            float mn = fmaxf(ma, mb);
            rs[tid] = rs[tid] * __expf(ma - mn) + rs[tid + off] * __expf(mb - mn);
            rm[tid] = mn;
        }
        __syncthreads();
    }
    if (tid == 0)
        rl[m] = logf(rs[0]) + rm[0] - logits[(size_t)m * VV + y[m]];
}

// ---------------- MFMA flash attention (quirk: k plays query role), LPT dispatch
__global__ __launch_bounds__(256) void attn_mfma(const __hip_bfloat16* __restrict__ kq,
                                                 const __hip_bfloat16* __restrict__ qk,
                                                 const __hip_bfloat16* __restrict__ vt,
                                                 __hip_bfloat16* __restrict__ oc) {
    __shared__ __hip_bfloat16 Qs[2][KVBLK * 64];
    __shared__ __hip_bfloat16 Vs[2][64 * KVBLK];
    __shared__ __hip_bfloat16 Ps[QBLK * KVBLK];
    int tid = threadIdx.x;
    int l = tid & 63, w = tid >> 6;
    int t0 = (int)(gridDim.x - 1 - blockIdx.x) * QBLK;
    size_t bh = (size_t)(blockIdx.z * HH + blockIdx.y);
    const __hip_bfloat16* kqp = kq + bh * TT * DD;
    const __hip_bfloat16* qkp = qk + bh * TT * DD;
    const __hip_bfloat16* vtp = vt + bh * DD * TT;

    bf16x8 af[2][2];
    #pragma unroll
    for (int i = 0; i < 2; i++)
        #pragma unroll
        for (int ks = 0; ks < 2; ks++)
            af[i][ks] = *(const bf16x8*)&kqp[(size_t)(t0 + w * 32 + i * 16 + (l & 15)) * DD
                                             + ks * 32 + (l >> 4) * 8];

    f32x4 acc_o[2][4] = {};
    float mrow[2][4], lrow[2][4];
    #pragma unroll
    for (int i = 0; i < 2; i++)
        #pragma unroll
        for (int r = 0; r < 4; r++) { mrow[i][r] = -1e30f; lrow[i][r] = 0.f; }

    auto stageKV = [&](int pp, int s0) {
        #pragma unroll
        for (int it = 0; it < 2; it++) {
            int chunk = w * 2 + it;
            int o = chunk * 1024 + l * 16;
            int row = o >> 7;
            int cb = (o & 127) ^ ((row & 7) << 4);
            gload_lds16(qkp + (size_t)(s0 + row) * DD + (cb >> 1),
                        (char*)Qs[pp] + chunk * 1024);
            gload_lds16(vtp + (size_t)row * TT + s0 + (cb >> 1),
                        (char*)Vs[pp] + chunk * 1024);
        }
    };

    int nt = (t0 + QBLK) / KVBLK;
    stageKV(0, 0);
    int p = 0;
    for (int ti = 0; ti < nt; ti++) {
        int s0 = ti * KVBLK;
        __syncthreads();
        if (ti + 1 < nt) stageKV(p ^ 1, s0 + KVBLK);

        f32x4 sa[2][4] = {};
        #pragma unroll
        for (int ks = 0; ks < 2; ks++) {
            bf16x8 bfr[4];
            #pragma unroll
            for (int j = 0; j < 4; j++) {
                int row = j * 16 + (l & 15);
                int cb = (ks * 64 + (l >> 4) * 16) ^ ((row & 7) << 4);
                bfr[j] = *(const bf16x8*)((const char*)Qs[p] + row * 128 + cb);
            }
            #pragma unroll
            for (int i = 0; i < 2; i++)
                #pragma unroll
                for (int j = 0; j < 4; j++)
                    sa[i][j] = __builtin_amdgcn_mfma_f32_16x16x32_bf16(af[i][ks], bfr[j], sa[i][j], 0, 0, 0);
        }

        #pragma unroll
        for (int i = 0; i < 2; i++) {
            #pragma unroll
            for (int r = 0; r < 4; r++) {
                int t = t0 + w * 32 + i * 16 + (l >> 4) * 4 + r;
                float pv[4];
                float rmax = -1e30f;
                #pragma unroll
                for (int j = 0; j < 4; j++) {
                    int s = s0 + j * 16 + (l & 15);
                    float v = sa[i][j][r] * 0.125f;
                    v = (s <= t) ? v : -1e30f;
                    pv[j] = v;
                    rmax = fmaxf(rmax, v);
                }
                #pragma unroll
                for (int msk = 1; msk < 16; msk <<= 1)
                    rmax = fmaxf(rmax, __shfl_xor(rmax, msk));
                float mo = mrow[i][r];
                float mn = fmaxf(mo, rmax);
                float fac = __expf(mo - mn);
                float ls = 0.f;
                int prow = w * 32 + i * 16 + (l >> 4) * 4 + r;
                #pragma unroll
                for (int j = 0; j < 4; j++) {
                    float e = __expf(pv[j] - mn);
                    ls += e;
                    int cb = (j * 32 + (l & 15) * 2) ^ ((prow & 7) << 4);
                    *(__hip_bfloat16*)((char*)Ps + prow * 128 + cb) = __float2bfloat16(e);
                }
                #pragma unroll
                for (int msk = 1; msk < 16; msk <<= 1)
                    ls += __shfl_xor(ls, msk);
                mrow[i][r] = mn;
                lrow[i][r] = lrow[i][r] * fac + ls;
                #pragma unroll
                for (int jd = 0; jd < 4; jd++)
                    acc_o[i][jd][r] *= fac;
            }
        }

        #pragma unroll
        for (int ks = 0; ks < 2; ks++) {
            bf16x8 pa[2], vf[4];
            #pragma unroll
            for (int i = 0; i < 2; i++) {
                int row = w * 32 + i * 16 + (l & 15);
                int cb = (ks * 64 + (l >> 4) * 16) ^ ((row & 7) << 4);
                pa[i] = *(const bf16x8*)((const char*)Ps + row * 128 + cb);
            }
            #pragma unroll
            for (int jd = 0; jd < 4; jd++) {
                int row = jd * 16 + (l & 15);
                int cb = (ks * 64 + (l >> 4) * 16) ^ ((row & 7) << 4);
                vf[jd] = *(const bf16x8*)((const char*)Vs[p] + row * 128 + cb);
            }
            #pragma unroll
            for (int i = 0; i < 2; i++)
                #pragma unroll
                for (int jd = 0; jd < 4; jd++)
                    acc_o[i][jd] = __builtin_amdgcn_mfma_f32_16x16x32_bf16(pa[i], vf[jd], acc_o[i][jd], 0, 0, 0);
        }
        p ^= 1;
    }

    int b = blockIdx.z, hh = blockIdx.y;
    #pragma unroll
    for (int i = 0; i < 2; i++) {
        #pragma unroll
        for (int r = 0; r < 4; r++) {
            float inv = 1.f / lrow[i][r];
            int t = t0 + w * 32 + i * 16 + (l >> 4) * 4 + r;
            #pragma unroll
            for (int jd = 0; jd < 4; jd++) {
                int d = jd * 16 + (l & 15);
                oc[((size_t)(b * TT + t)) * CC + hh * DD + d] =
                    __float2bfloat16(acc_o[i][jd][r] * inv);
            }
        }
    }
}

// ---------------- hb = bf16(LN(bf16(hb) + t)) — wave-reduce version (2 barriers)
__global__ __launch_bounds__(256) void resid_ln(__hip_bfloat16* __restrict__ hb,
                                                const float* __restrict__ t,
                                                const float* __restrict__ g,
                                                const float* __restrict__ bta) {
    int row = blockIdx.x;
    int tid = threadIdx.x;
    int l = tid & 63, w = tid >> 6;
    __shared__ float pa[4], pb[4];
    float x[3];
    float s = 0.f;
    #pragma unroll
    for (int i = 0; i < 3; i++) {
        int c = tid + i * 256;
        x[i] = __bfloat162float(hb[(size_t)row * CC + c]) + t[(size_t)row * CC + c];
        s += x[i];
    }
    #pragma unroll
    for (int msk = 1; msk < 64; msk <<= 1) s += __shfl_xor(s, msk);
    if (l == 0) pa[w] = s;
    __syncthreads();
    float mean = (pa[0] + pa[1] + pa[2] + pa[3]) * (1.f / CC);
    float s2 = 0.f;
    #pragma unroll
    for (int i = 0; i < 3; i++) { float dd = x[i] - mean; s2 += dd * dd; }
    #pragma unroll
    for (int msk = 1; msk < 64; msk <<= 1) s2 += __shfl_xor(s2, msk);
    if (l == 0) pb[w] = s2;
    __syncthreads();
    float inv = rsqrtf((pb[0] + pb[1] + pb[2] + pb[3]) * (1.f / CC) + 1e-5f);
    #pragma unroll
    for (int i = 0; i < 3; i++) {
        int c = tid + i * 256;
        hb[(size_t)row * CC + c] = __float2bfloat16((x[i] - mean) * inv * g[c] + bta[c]);
    }
}

__global__ __launch_bounds__(256) void loss_reduce(const float* __restrict__ rl,
                                                   float* __restrict__ out) {
    int tid = threadIdx.x;
    __shared__ float red[256];
    float s = 0.f;
    for (int i = tid; i < MROWS; i += 256) s += rl[i];
    red[tid] = s; __syncthreads();
    for (int off = 128; off > 0; off >>= 1) {
        if (tid < off) red[tid] += red[tid + off];
        __syncthreads();
    }
    if (tid == 0) out[0] = red[0] * (1.f / MROWS);
}

extern "C" void kernel_launch(void* const* d_in, const int* in_sizes, int n_in,
                              void* d_out, int out_size, void* d_ws, size_t ws_size,
                              hipStream_t stream) {
    const int*   x     = (const int*)d_in[0];
    const int*   y     = (const int*)d_in[1];
    const float* tok   = (const float*)d_in[2];
    const float* pos   = (const float*)d_in[3];
    const float* Wk    = (const float*)d_in[4];
    const float* Wq    = (const float*)d_in[5];
    const float* Wv    = (const float*)d_in[6];
    const float* Wproj = (const float*)d_in[7];
    const float* bproj = (const float*)d_in[8];
    const float* ln1g  = (const float*)d_in[9];
    const float* ln1b  = (const float*)d_in[10];
    const float* W1    = (const float*)d_in[11];
    const float* b1    = (const float*)d_in[12];
    const float* W2    = (const float*)d_in[13];
    const float* b2    = (const float*)d_in[14];
    const float* ln2g  = (const float*)d_in[15];
    const float* ln2b  = (const float*)d_in[16];
    const float* Wlm   = (const float*)d_in[17];
    const float* blm   = (const float*)d_in[18];

    float* logits = (float*)d_out;
    float* lossp  = (float*)d_out + ((size_t)out_size - 1);

    char* p = (char*)d_ws;
    auto alloc = [&](size_t bytes) { char* r = p; p += (bytes + 255) & ~255ULL; return r; };
    const size_t S_HC = (size_t)MROWS * CC;

    float* tmpf = (float*)alloc(S_HC * 4);
    float* rl   = (float*)alloc(MROWS * 4);
    float* pm   = (float*)alloc((size_t)MROWS * NPART * 4);
    float* ps   = (float*)alloc((size_t)MROWS * NPART * 4);
    __hip_bfloat16* kbb  = (__hip_bfloat16*)alloc(S_HC * 2);
    __hip_bfloat16* qbb  = (__hip_bfloat16*)alloc(S_HC * 2);
    __hip_bfloat16* vtb  = (__hip_bfloat16*)alloc(S_HC * 2);
    __hip_bfloat16* hb   = (__hip_bfloat16*)alloc(S_HC * 2);
    __hip_bfloat16* ocb  = (__hip_bfloat16*)alloc(S_HC * 2);
    __hip_bfloat16* ff1b = (__hip_bfloat16*)alloc((size_t)MROWS * FFH * 2);
    __hip_bfloat16* kT   = (__hip_bfloat16*)alloc((size_t)LL * CC * CC * 2);
    __hip_bfloat16* qT   = (__hip_bfloat16*)alloc((size_t)LL * CC * CC * 2);
    __hip_bfloat16* vT   = (__hip_bfloat16*)alloc((size_t)LL * CC * CC * 2);
    __hip_bfloat16* pT   = (__hip_bfloat16*)alloc((size_t)LL * CC * CC * 2);
    __hip_bfloat16* w1T  = (__hip_bfloat16*)alloc((size_t)LL * CC * FFH * 2);
    __hip_bfloat16* w2T  = (__hip_bfloat16*)alloc((size_t)LL * FFH * CC * 2);
    __hip_bfloat16* lmT  = (__hip_bfloat16*)alloc((size_t)VPAD2 * CC * 2);

    dim3 blk(256);

    cvtT_qkv<<<dim3(24, 2, 3 * 144), blk, 0, stream>>>(Wk, Wq, Wv, kT, qT, vT);
    cvtT_mat<<<dim3(24, 24, LL), blk, 0, stream>>>(Wproj, pT, CC, CC,
                                                   (size_t)CC * CC, (size_t)CC * CC);
    cvtT_mat<<<dim3(96, 24, LL), blk, 0, stream>>>(W1, w1T, CC, FFH,
                                                   (size_t)CC * FFH, (size_t)FFH * CC);
    cvtT_mat<<<dim3(24, 96, LL), blk, 0, stream>>>(W2, w2T, FFH, CC,
                                                   (size_t)FFH * CC, (size_t)CC * FFH);
    cvtT_mat<<<dim3(VPAD2 / 32, 24, 1), blk, 0, stream>>>(Wlm, lmT, CC, VV, 0, 0);

    embed_kernel<<<dim3((MROWS * CC + 255) / 256), blk, 0, stream>>>(x, tok, pos, hb);

    for (int l = 0; l < LL; l++) {
        const __hip_bfloat16* kT_l = kT + (size_t)l * CC * CC;
        const __hip_bfloat16* qT_l = qT + (size_t)l * CC * CC;
        const __hip_bfloat16* vT_l = vT + (size_t)l * CC * CC;
        const __hip_bfloat16* pT_l = pT + (size_t)l * CC * CC;
        const __hip_bfloat16* w1T_l = w1T + (size_t)l * CC * FFH;
        const __hip_bfloat16* w2T_l = w2T + (size_t)l * FFH * CC;

        gemm_qkv_n64<<<dim3(CC / 64, MROWS / 128, 3), blk, 0, stream>>>(
            hb, kT_l, qT_l, vT_l, kbb, qbb, vtb);
        attn_mfma<<<dim3(TT / QBLK, HH, BB), blk, 0, stream>>>(kbb, qbb, vtb, ocb);
        gemm_mfma_n64<<<dim3(CC / 64, MROWS / 128), blk, 0, stream>>>(
            ocb, pT_l, bproj + (size_t)l * CC, tmpf, MROWS, CC, CC, 0);
        resid_ln<<<dim3(MROWS), blk, 0, stream>>>(hb, tmpf, ln1g + (size_t)l * CC,
                                                  ln1b + (size_t)l * CC);
        gemm_mfma<<<dim3(FFH / 128, MROWS / 128), blk, 0, stream>>>(
            hb, w1T_l, b1 + (size_t)l * FFH, (float*)nullptr, ff1b,
            MROWS, FFH, CC, 1);
        gemm_mfma_n64<<<dim3(CC / 64, MROWS / 128), blk, 0, stream>>>(
            ff1b, w2T_l, b2 + (size_t)l * CC, tmpf, MROWS, CC, FFH, 0);
        resid_ln<<<dim3(MROWS), blk, 0, stream>>>(hb, tmpf, ln2g + (size_t)l * CC,
                                                  ln2b + (size_t)l * CC);
    }

    lm_head_mfma256<<<dim3(MROWS / 256, VPAD2 / 256), dim3(512), 0, stream>>>(
        hb, lmT, blm, logits, pm, ps);
    nll_combine<<<dim3(MROWS), blk, 0, stream>>>(pm, ps, logits, y, rl);
    loss_reduce<<<dim3(1), blk, 0, stream>>>(rl, lossp);
}

// Round 16
// 3104.240 us; speedup vs baseline: 1.0161x; 1.0007x over previous
//
#include <hip/hip_runtime.h>
#include <hip/hip_bf16.h>
#include <math.h>

#define BB 4
#define TT 1024
#define VV 50257
#define VPAD2 50432
#define CC 768
#define HH 12
#define DD 64
#define LL 12
#define FFH 3072
#define MROWS (BB*TT)   // 4096
#define QBLK 128
#define KVBLK 64
#define NPART (VPAD2 / 64)        // 788 partials per row

typedef __bf16 bf16x8 __attribute__((ext_vector_type(8)));
typedef float  f32x4  __attribute__((ext_vector_type(4)));
typedef unsigned int u32;
#define AS1 __attribute__((address_space(1)))
#define AS3 __attribute__((address_space(3)))

static __device__ __forceinline__ void gload_lds16(const void* g, void* l) {
    __builtin_amdgcn_global_load_lds((const AS1 u32*)g, (AS3 u32*)l, 16, 0, 0);
}

// stage one 128x64 bf16 tile pair into linear LDS, source pre-swizzled (4 waves)
static __device__ __forceinline__ void stage_tile(const __hip_bfloat16* __restrict__ A,
                                                  const __hip_bfloat16* __restrict__ Bt,
                                                  int Kld, int k0, int bm, int bn,
                                                  int w, int l, char* As, char* Bs) {
    #pragma unroll
    for (int it = 0; it < 4; it++) {
        int chunk = w * 4 + it;
        int o = chunk * 1024 + l * 16;
        int row = o >> 7;
        int cb = (o & 127) ^ ((row & 7) << 4);
        gload_lds16(A + (size_t)(bm + row) * Kld + k0 + (cb >> 1), As + chunk * 1024);
        gload_lds16(Bt + (size_t)(bn + row) * Kld + k0 + (cb >> 1), Bs + chunk * 1024);
    }
}

// stage A(128x64) + B(64x64) for the n64 tile (4 waves)
static __device__ __forceinline__ void stage_tile_n64(const __hip_bfloat16* __restrict__ A,
                                                      const __hip_bfloat16* __restrict__ Bt,
                                                      int Kld, int k0, int bm, int bn,
                                                      int w, int l, char* As, char* Bs) {
    #pragma unroll
    for (int it = 0; it < 4; it++) {
        int chunk = w * 4 + it;
        int o = chunk * 1024 + l * 16;
        int row = o >> 7;
        int cb = (o & 127) ^ ((row & 7) << 4);
        gload_lds16(A + (size_t)(bm + row) * Kld + k0 + (cb >> 1), As + chunk * 1024);
    }
    #pragma unroll
    for (int it = 0; it < 2; it++) {
        int chunk = w * 2 + it;
        int o = chunk * 1024 + l * 16;
        int row = o >> 7;
        int cb = (o & 127) ^ ((row & 7) << 4);
        gload_lds16(Bt + (size_t)(bn + row) * Kld + k0 + (cb >> 1), Bs + chunk * 1024);
    }
}

// stage one 128-row x 64-col half-tile of ONE tensor (16KB; 512 threads x 2 loads)
static __device__ __forceinline__ void stage_half(const __hip_bfloat16* __restrict__ src,
                                                  int Kld, int k0, int rowbase,
                                                  char* dst, int w, int l) {
    #pragma unroll
    for (int it = 0; it < 2; it++) {
        int chunk = w * 2 + it;
        int o = chunk * 1024 + l * 16;
        int row = o >> 7;
        int cb = (o & 127) ^ ((row & 7) << 4);
        gload_lds16(src + (size_t)(rowbase + row) * Kld + k0 + (cb >> 1), dst + chunk * 1024);
    }
}

// ---------------- embedding (bf16 residual stream)
__global__ void embed_kernel(const int* __restrict__ x, const float* __restrict__ tok,
                             const float* __restrict__ pos,
                             __hip_bfloat16* __restrict__ hb) {
    int idx = blockIdx.x * 256 + threadIdx.x;
    if (idx >= MROWS * CC) return;
    int row = idx / CC, c = idx - row * CC;
    int id = x[row];
    hb[idx] = __float2bfloat16(tok[(size_t)id * CC + c] + pos[(size_t)id * CC + c]);
}

// ---------------- convert + transpose weights
__global__ __launch_bounds__(256) void cvtT_mat(const float* __restrict__ in,
                                                __hip_bfloat16* __restrict__ out,
                                                int K, int Nin,
                                                size_t ibs, size_t obs) {
    __shared__ float t[32][33];
    const float* ip = in + blockIdx.z * ibs;
    __hip_bfloat16* op = out + blockIdx.z * obs;
    int n0 = blockIdx.x * 32, k0 = blockIdx.y * 32;
    int tx = threadIdx.x & 31, ty = threadIdx.x >> 5;
    #pragma unroll
    for (int i = 0; i < 4; i++) {
        int k = k0 + ty + i * 8, n = n0 + tx;
        t[ty + i * 8][tx] = (n < Nin) ? ip[(size_t)k * Nin + n] : 0.f;
    }
    __syncthreads();
    #pragma unroll
    for (int i = 0; i < 4; i++) {
        int n = n0 + ty + i * 8, k = k0 + tx;
        op[(size_t)n * K + k] = __float2bfloat16(t[tx][ty + i * 8]);
    }
}

__global__ __launch_bounds__(256) void cvtT_qkv(const float* __restrict__ Wk,
                                                const float* __restrict__ Wq,
                                                const float* __restrict__ Wv,
                                                __hip_bfloat16* __restrict__ kT,
                                                __hip_bfloat16* __restrict__ qT,
                                                __hip_bfloat16* __restrict__ vT) {
    int z = blockIdx.z;
    int tensor = z / 144, lh = z % 144;
    int l = lh / HH, hh = lh % HH;
    const float* in = (tensor == 0 ? Wk : tensor == 1 ? Wq : Wv) + (size_t)lh * CC * DD;
    __hip_bfloat16* out = (tensor == 0 ? kT : tensor == 1 ? qT : vT)
                          + ((size_t)l * CC + hh * DD) * CC;
    __shared__ float t[32][33];
    int c0 = blockIdx.x * 32, d0 = blockIdx.y * 32;
    int tx = threadIdx.x & 31, ty = threadIdx.x >> 5;
    #pragma unroll
    for (int i = 0; i < 4; i++)
        t[ty + i * 8][tx] = in[(size_t)(c0 + ty + i * 8) * DD + d0 + tx];
    __syncthreads();
    #pragma unroll
    for (int i = 0; i < 4; i++)
        out[(size_t)(d0 + ty + i * 8) * CC + c0 + tx] = __float2bfloat16(t[tx][ty + i * 8]);
}

// ---------------- MFMA GEMM 128x128 dbuf + LDS-staged coalesced epilogue (ffn1: bf16 out).
__global__ __launch_bounds__(256) void gemm_mfma(const __hip_bfloat16* __restrict__ A,
                                                 const __hip_bfloat16* __restrict__ Bt,
                                                 const float* __restrict__ bias,
                                                 __hip_bfloat16* __restrict__ Cb,
                                                 int M, int N, int K, int relu) {
    __shared__ __align__(16) char smem[65536];
    int tid = threadIdx.x;
    int l = tid & 63, w = tid >> 6;
    int wr = w >> 1, wc = w & 1;
    int bm = blockIdx.y * 128, bn = blockIdx.x * 128;

    f32x4 acc[4][4] = {};

    stage_tile(A, Bt, K, 0, bm, bn, w, l, smem, smem + 32768);
    int p = 0;
    for (int k0 = 0; k0 < K; k0 += 64) {
        __syncthreads();
        if (k0 + 64 < K)
            stage_tile(A, Bt, K, k0 + 64, bm, bn, w, l,
                       smem + (p ^ 1) * 16384, smem + 32768 + (p ^ 1) * 16384);
        const char* Ab = smem + p * 16384;
        const char* Bb = smem + 32768 + p * 16384;
        #pragma unroll
        for (int ks = 0; ks < 2; ks++) {
            bf16x8 af[4], bfr[4];
            #pragma unroll
            for (int i = 0; i < 4; i++) {
                int row = wr * 64 + i * 16 + (l & 15);
                int cb = (ks * 64 + (l >> 4) * 16) ^ ((row & 7) << 4);
                af[i] = *(const bf16x8*)(Ab + row * 128 + cb);
            }
            #pragma unroll
            for (int j = 0; j < 4; j++) {
                int row = wc * 64 + j * 16 + (l & 15);
                int cb = (ks * 64 + (l >> 4) * 16) ^ ((row & 7) << 4);
                bfr[j] = *(const bf16x8*)(Bb + row * 128 + cb);
            }
            #pragma unroll
            for (int i = 0; i < 4; i++)
                #pragma unroll
                for (int j = 0; j < 4; j++)
                    acc[i][j] = __builtin_amdgcn_mfma_f32_16x16x32_bf16(af[i], bfr[j], acc[i][j], 0, 0, 0);
        }
        p ^= 1;
    }

    __hip_bfloat16* ebh = (__hip_bfloat16*)smem;
    __syncthreads();
    #pragma unroll
    for (int i = 0; i < 4; i++) {
        #pragma unroll
        for (int j = 0; j < 4; j++) {
            int colt = wc * 64 + j * 16 + (l & 15);
            float bv = bias ? bias[bn + colt] : 0.f;
            #pragma unroll
            for (int r = 0; r < 4; r++) {
                int rowc = wr * 64 + i * 16 + (l >> 4) * 4 + r;
                float v = acc[i][j][r] + bv;
                if (relu) v = fmaxf(v, 0.f);
                ebh[rowc * 136 + colt] = __float2bfloat16(v);
            }
        }
    }
    __syncthreads();
    #pragma unroll
    for (int pass = 0; pass < 8; pass++) {
        int idx = pass * 256 + tid;
        int rowc = idx >> 4, colq = idx & 15;
        *(bf16x8*)&Cb[(size_t)(bm + rowc) * N + bn + colq * 8] =
            *(const bf16x8*)&ebh[rowc * 136 + colq * 8];
    }
}

// ---------------- MFMA GEMM 128x64 + fused residual add, bf16 out (proj/ffn2)
__global__ __launch_bounds__(256) void gemm_mfma_n64r(const __hip_bfloat16* __restrict__ A,
                                                      const __hip_bfloat16* __restrict__ Bt,
                                                      const float* __restrict__ bias,
                                                      const __hip_bfloat16* __restrict__ resid,
                                                      __hip_bfloat16* __restrict__ Cb,
                                                      int M, int N, int K) {
    __shared__ __align__(16) char smem[49152];
    int tid = threadIdx.x;
    int l = tid & 63, w = tid >> 6;
    int bm = blockIdx.y * 128, bn = blockIdx.x * 64;

    f32x4 acc[2][4] = {};

    stage_tile_n64(A, Bt, K, 0, bm, bn, w, l, smem, smem + 32768);
    int p = 0;
    for (int k0 = 0; k0 < K; k0 += 64) {
        __syncthreads();
        if (k0 + 64 < K)
            stage_tile_n64(A, Bt, K, k0 + 64, bm, bn, w, l,
                           smem + (p ^ 1) * 16384, smem + 32768 + (p ^ 1) * 8192);
        const char* Ab = smem + p * 16384;
        const char* Bb = smem + 32768 + p * 8192;
        #pragma unroll
        for (int ks = 0; ks < 2; ks++) {
            bf16x8 af[2], bfr[4];
            #pragma unroll
            for (int i = 0; i < 2; i++) {
                int row = w * 32 + i * 16 + (l & 15);
                int cb = (ks * 64 + (l >> 4) * 16) ^ ((row & 7) << 4);
                af[i] = *(const bf16x8*)(Ab + row * 128 + cb);
            }
            #pragma unroll
            for (int j = 0; j < 4; j++) {
                int row = j * 16 + (l & 15);
                int cb = (ks * 64 + (l >> 4) * 16) ^ ((row & 7) << 4);
                bfr[j] = *(const bf16x8*)(Bb + row * 128 + cb);
            }
            #pragma unroll
            for (int i = 0; i < 2; i++)
                #pragma unroll
                for (int j = 0; j < 4; j++)
                    acc[i][j] = __builtin_amdgcn_mfma_f32_16x16x32_bf16(af[i], bfr[j], acc[i][j], 0, 0, 0);
        }
        p ^= 1;
    }

    __hip_bfloat16* eb = (__hip_bfloat16*)smem;
    __syncthreads();
    #pragma unroll
    for (int i = 0; i < 2; i++) {
        #pragma unroll
        for (int j = 0; j < 4; j++) {
            int colt = j * 16 + (l & 15);
            float bv = bias[bn + colt];
            #pragma unroll
            for (int r = 0; r < 4; r++) {
                int rowc = w * 32 + i * 16 + (l >> 4) * 4 + r;
                float rv = __bfloat162float(resid[(size_t)(bm + rowc) * N + bn + colt]);
                eb[rowc * 72 + colt] = __float2bfloat16(acc[i][j][r] + bv + rv);
            }
        }
    }
    __syncthreads();
    #pragma unroll
    for (int pass = 0; pass < 4; pass++) {
        int idx = pass * 256 + tid;
        int rowc = idx >> 3, colq = idx & 7;
        *(bf16x8*)&Cb[(size_t)(bm + rowc) * N + bn + colq * 8] =
            *(const bf16x8*)&eb[rowc * 72 + colq * 8];
    }
}

// ---------------- QKV GEMM 128x64 tile; bn spans ONE head.
__global__ __launch_bounds__(256) void gemm_qkv_n64(const __hip_bfloat16* __restrict__ A,
                                                    const __hip_bfloat16* __restrict__ kT,
                                                    const __hip_bfloat16* __restrict__ qT,
                                                    const __hip_bfloat16* __restrict__ vT,
                                                    __hip_bfloat16* __restrict__ ko,
                                                    __hip_bfloat16* __restrict__ qo,
                                                    __hip_bfloat16* __restrict__ vto) {
    const __hip_bfloat16* Bt = (blockIdx.z == 0) ? kT : (blockIdx.z == 1) ? qT : vT;
    __shared__ __align__(16) char smem[49152];
    int tid = threadIdx.x;
    int l = tid & 63, w = tid >> 6;
    int bm = blockIdx.y * 128, bn = blockIdx.x * 64;

    f32x4 acc[2][4] = {};

    stage_tile_n64(A, Bt, CC, 0, bm, bn, w, l, smem, smem + 32768);
    int p = 0;
    for (int k0 = 0; k0 < CC; k0 += 64) {
        __syncthreads();
        if (k0 + 64 < CC)
            stage_tile_n64(A, Bt, CC, k0 + 64, bm, bn, w, l,
                           smem + (p ^ 1) * 16384, smem + 32768 + (p ^ 1) * 8192);
        const char* Ab = smem + p * 16384;
        const char* Bb = smem + 32768 + p * 8192;
        #pragma unroll
        for (int ks = 0; ks < 2; ks++) {
            bf16x8 af[2], bfr[4];
            #pragma unroll
            for (int i = 0; i < 2; i++) {
                int row = w * 32 + i * 16 + (l & 15);
                int cb = (ks * 64 + (l >> 4) * 16) ^ ((row & 7) << 4);
                af[i] = *(const bf16x8*)(Ab + row * 128 + cb);
            }
            #pragma unroll
            for (int j = 0; j < 4; j++) {
                int row = j * 16 + (l & 15);
                int cb = (ks * 64 + (l >> 4) * 16) ^ ((row & 7) << 4);
                bfr[j] = *(const bf16x8*)(Bb + row * 128 + cb);
            }
            #pragma unroll
            for (int i = 0; i < 2; i++)
                #pragma unroll
                for (int j = 0; j < 4; j++)
                    acc[i][j] = __builtin_amdgcn_mfma_f32_16x16x32_bf16(af[i], bfr[j], acc[i][j], 0, 0, 0);
        }
        p ^= 1;
    }

    int zz = blockIdx.z;
    int b = bm >> 10, tbase = bm & 1023, head = bn >> 6;
    __hip_bfloat16* eb = (__hip_bfloat16*)smem;
    __syncthreads();
    if (zz != 2) {
        #pragma unroll
        for (int i = 0; i < 2; i++)
            #pragma unroll
            for (int j = 0; j < 4; j++) {
                int colt = j * 16 + (l & 15);
                #pragma unroll
                for (int r = 0; r < 4; r++) {
                    int rowc = w * 32 + i * 16 + (l >> 4) * 4 + r;
                    eb[rowc * 72 + colt] = __float2bfloat16(acc[i][j][r]);
                }
            }
        __syncthreads();
        __hip_bfloat16* O = (zz == 0) ? ko : qo;
        #pragma unroll
        for (int pass = 0; pass < 4; pass++) {
            int idx = pass * 256 + tid;
            int rowc = idx >> 3, colq = idx & 7;
            *(bf16x8*)&O[(((size_t)(b * HH + head)) * TT + tbase + rowc) * DD + colq * 8] =
                *(const bf16x8*)&eb[rowc * 72 + colq * 8];
        }
    } else {
        #pragma unroll
        for (int i = 0; i < 2; i++)
            #pragma unroll
            for (int j = 0; j < 4; j++) {
                int colt = j * 16 + (l & 15);
                #pragma unroll
                for (int r = 0; r < 4; r++) {
                    int rowc = w * 32 + i * 16 + (l >> 4) * 4 + r;
                    eb[colt * 136 + rowc] = __float2bfloat16(acc[i][j][r]);
                }
            }
        __syncthreads();
        #pragma unroll
        for (int pass = 0; pass < 4; pass++) {
            int idx = pass * 256 + tid;
            int line = idx >> 4, tq = idx & 15;
            *(bf16x8*)&vto[(((size_t)(b * HH + head)) * DD + line) * TT + tbase + tq * 8] =
                *(const bf16x8*)&eb[line * 136 + tq * 8];
        }
    }
}

// ---------------- LM head: 256x256, 8 waves, 8-phase counted-vmcnt pipeline (T3+T4+T5).
__global__ __launch_bounds__(512) void lm_head_mfma256(const __hip_bfloat16* __restrict__ A,
                                                       const __hip_bfloat16* __restrict__ Bt,
                                                       const float* __restrict__ bias,
                                                       float* __restrict__ Cf,
                                                       float* __restrict__ pm,
                                                       float* __restrict__ ps) {
    __shared__ __align__(16) char smem[131072];
    int tid = threadIdx.x;
    int l = tid & 63, w = tid >> 6;
    int wr = w >> 2, wc = w & 3;
    int bm = blockIdx.x * 256, bn = blockIdx.y * 256;

    f32x4 acc[8][4] = {};
    const int NT = CC / 64;

    stage_half(A,  CC, 0,  bm,       smem + 0,                 w, l);
    stage_half(A,  CC, 0,  bm + 128, smem + 16384,             w, l);
    stage_half(Bt, CC, 0,  bn,       smem + 65536,             w, l);
    stage_half(Bt, CC, 0,  bn + 128, smem + 65536 + 16384,     w, l);
    stage_half(Bt, CC, 64, bn,       smem + 65536 + 32768,     w, l);
    stage_half(Bt, CC, 64, bn + 128, smem + 65536 + 49152,     w, l);
    asm volatile("s_waitcnt vmcnt(4)\ns_barrier" ::: "memory");

    for (int kt = 0; kt < NT; kt++) {
        int db = kt & 1;
        const char* Ab = smem + db * 32768 + wr * 16384;
        const char* Bb = smem + 65536 + db * 32768;

        bf16x8 bfr[4][2];
        #pragma unroll
        for (int j = 0; j < 4; j++)
            #pragma unroll
            for (int ks = 0; ks < 2; ks++) {
                int RB = wc * 64 + j * 16 + (l & 15);
                int rB = RB & 127;
                int cb = (ks * 64 + (l >> 4) * 16) ^ ((rB & 7) << 4);
                bfr[j][ks] = *(const bf16x8*)(Bb + (RB >> 7) * 16384 + rB * 128 + cb);
            }

        #pragma unroll
        for (int q = 0; q < 4; q++) {
            bf16x8 af[2][2];
            #pragma unroll
            for (int ii = 0; ii < 2; ii++)
                #pragma unroll
                for (int ks = 0; ks < 2; ks++) {
                    int r = (2 * q + ii) * 16 + (l & 15);
                    int cb = (ks * 64 + (l >> 4) * 16) ^ ((r & 7) << 4);
                    af[ii][ks] = *(const bf16x8*)(Ab + r * 128 + cb);
                }
            if (q == 0 && kt + 1 < NT)
                stage_half(A, CC, (kt + 1) * 64, bm,
                           smem + ((kt + 1) & 1) * 32768, w, l);
            if (q == 1 && kt + 1 < NT)
                stage_half(A, CC, (kt + 1) * 64, bm + 128,
                           smem + ((kt + 1) & 1) * 32768 + 16384, w, l);
            if (q == 2 && kt + 2 < NT)
                stage_half(Bt, CC, (kt + 2) * 64, bn,
                           smem + 65536 + db * 32768, w, l);
            if (q == 3 && kt + 2 < NT)
                stage_half(Bt, CC, (kt + 2) * 64, bn + 128,
                           smem + 65536 + db * 32768 + 16384, w, l);

            asm volatile("s_barrier" ::: "memory");
            __builtin_amdgcn_s_setprio(1);
            #pragma unroll
            for (int ks = 0; ks < 2; ks++)
                #pragma unroll
                for (int ii = 0; ii < 2; ii++)
                    #pragma unroll
                    for (int j = 0; j < 4; j++)
                        acc[2 * q + ii][j] = __builtin_amdgcn_mfma_f32_16x16x32_bf16(
                            af[ii][ks], bfr[j][ks], acc[2 * q + ii][j], 0, 0, 0);
            __builtin_amdgcn_s_setprio(0);
            if (q < 3) asm volatile("s_barrier" ::: "memory");
        }
        if (kt == NT - 2)      asm volatile("s_waitcnt vmcnt(0)\ns_barrier" ::: "memory");
        else if (kt < NT - 1)  asm volatile("s_waitcnt vmcnt(4)\ns_barrier" ::: "memory");
    }
    __syncthreads();

    #pragma unroll
    for (int j = 0; j < 4; j++) {
        int col = bn + wc * 64 + j * 16 + (l & 15);
        float bv = (col < VV) ? bias[col] : 0.f;
        #pragma unroll
        for (int i = 0; i < 8; i++)
            #pragma unroll
            for (int r = 0; r < 4; r++)
                acc[i][j][r] += bv;
    }

    int pidx = blockIdx.y * 4 + wc;
    #pragma unroll
    for (int i = 0; i < 8; i++) {
        int row = bm + wr * 128 + i * 16 + (l >> 4) * 4;
        #pragma unroll
        for (int r = 0; r < 4; r++) {
            float pv[4];
            float rmax = -1e30f;
            #pragma unroll
            for (int j = 0; j < 4; j++) {
                int col = bn + wc * 64 + j * 16 + (l & 15);
                float v = (col < VV) ? acc[i][j][r] : -1e30f;
                pv[j] = v;
                rmax = fmaxf(rmax, v);
            }
            #pragma unroll
            for (int msk = 1; msk < 16; msk <<= 1)
                rmax = fmaxf(rmax, __shfl_xor(rmax, msk));
            float s = 0.f;
            #pragma unroll
            for (int j = 0; j < 4; j++) s += __expf(pv[j] - rmax);
            #pragma unroll
            for (int msk = 1; msk < 16; msk <<= 1)
                s += __shfl_xor(s, msk);
            if ((l & 15) == 0) {
                pm[(size_t)(row + r) * NPART + pidx] = rmax;
                ps[(size_t)(row + r) * NPART + pidx] = s;
            }
        }
    }

    // barrier-free per-wave staged epilogue (plain stores)
    float* eb0 = (float*)smem + (size_t)(w * 2 + 0) * (16 * 68);
    float* eb1 = (float*)smem + (size_t)(w * 2 + 1) * (16 * 68);
    int colg = bn + wc * 64 + l;
    bool valid = colg < VV;
    #pragma unroll
    for (int i = 0; i < 8; i++) {
        float* eb = (i & 1) ? eb1 : eb0;
        #pragma unroll
        for (int j = 0; j < 4; j++) {
            int colt = j * 16 + (l & 15);
            #pragma unroll
            for (int r = 0; r < 4; r++) {
                int rowc = (l >> 4) * 4 + r;
                eb[rowc * 68 + colt] = acc[i][j][r];
            }
        }
        int rowbase = bm + wr * 128 + i * 16;
        #pragma unroll
        for (int pp = 0; pp < 16; pp++) {
            float v = eb[pp * 68 + l];
            if (valid) Cf[(size_t)(rowbase + pp) * VV + colg] = v;
        }
    }
}

// ---------------- combine LSE partials -> per-row NLL
__global__ __launch_bounds__(256) void nll_combine(const float* __restrict__ pm,
                                                   const float* __restrict__ ps,
                                                   const float* __restrict__ logits,
                                                   const int* __restrict__ y,
                                                   float* __restrict__ rl) {
    int m = blockIdx.x, tid = threadIdx.x;
    __shared__ float rm[256], rs[256];
    float mt = -1e30f, st = 0.f;
    for (int i = tid; i < NPART; i += 256) {
        float mi = pm[(size_t)m * NPART + i];
        float si = ps[(size_t)m * NPART + i];
        float mn = fmaxf(mt, mi);
        st = st * __expf(mt - mn) + si * __expf(mi - mn);
        mt = mn;
    }
    rm[tid] = mt; rs[tid] = st; __syncthreads();
    for (int off = 128; off > 0; off >>= 1) {
        if (tid < off) {
            float ma = rm[tid], mb = rm[tid + off];
            float mn = fmaxf(ma, mb);
            rs[tid] = rs[tid] * __expf(ma - mn) + rs[tid + off] * __expf(mb - mn);
            rm[tid] = mn;
        }
        __syncthreads();
    }
    if (tid == 0)
        rl[m] = logf(rs[0]) + rm[0] - logits[(size_t)m * VV + y[m]];
}

// ---------------- MFMA flash attention (quirk: k plays query role), LPT dispatch
__global__ __launch_bounds__(256) void attn_mfma(const __hip_bfloat16* __restrict__ kq,
                                                 const __hip_bfloat16* __restrict__ qk,
                                                 const __hip_bfloat16* __restrict__ vt,
                                                 __hip_bfloat16* __restrict__ oc) {
    __shared__ __hip_bfloat16 Qs[2][KVBLK * 64];
    __shared__ __hip_bfloat16 Vs[2][64 * KVBLK];
    __shared__ __hip_bfloat16 Ps[QBLK * KVBLK];
    int tid = threadIdx.x;
    int l = tid & 63, w = tid >> 6;
    int t0 = (int)(gridDim.x - 1 - blockIdx.x) * QBLK;
    size_t bh = (size_t)(blockIdx.z * HH + blockIdx.y);
    const __hip_bfloat16* kqp = kq + bh * TT * DD;
    const __hip_bfloat16* qkp = qk + bh * TT * DD;
    const __hip_bfloat16* vtp = vt + bh * DD * TT;

    bf16x8 af[2][2];
    #pragma unroll
    for (int i = 0; i < 2; i++)
        #pragma unroll
        for (int ks = 0; ks < 2; ks++)
            af[i][ks] = *(const bf16x8*)&kqp[(size_t)(t0 + w * 32 + i * 16 + (l & 15)) * DD
                                             + ks * 32 + (l >> 4) * 8];

    f32x4 acc_o[2][4] = {};
    float mrow[2][4], lrow[2][4];
    #pragma unroll
    for (int i = 0; i < 2; i++)
        #pragma unroll
        for (int r = 0; r < 4; r++) { mrow[i][r] = -1e30f; lrow[i][r] = 0.f; }

    auto stageKV = [&](int pp, int s0) {
        #pragma unroll
        for (int it = 0; it < 2; it++) {
            int chunk = w * 2 + it;
            int o = chunk * 1024 + l * 16;
            int row = o >> 7;
            int cb = (o & 127) ^ ((row & 7) << 4);
            gload_lds16(qkp + (size_t)(s0 + row) * DD + (cb >> 1),
                        (char*)Qs[pp] + chunk * 1024);
            gload_lds16(vtp + (size_t)row * TT + s0 + (cb >> 1),
                        (char*)Vs[pp] + chunk * 1024);
        }
    };

    int nt = (t0 + QBLK) / KVBLK;
    stageKV(0, 0);
    int p = 0;
    for (int ti = 0; ti < nt; ti++) {
        int s0 = ti * KVBLK;
        __syncthreads();
        if (ti + 1 < nt) stageKV(p ^ 1, s0 + KVBLK);

        f32x4 sa[2][4] = {};
        #pragma unroll
        for (int ks = 0; ks < 2; ks++) {
            bf16x8 bfr[4];
            #pragma unroll
            for (int j = 0; j < 4; j++) {
                int row = j * 16 + (l & 15);
                int cb = (ks * 64 + (l >> 4) * 16) ^ ((row & 7) << 4);
                bfr[j] = *(const bf16x8*)((const char*)Qs[p] + row * 128 + cb);
            }
            #pragma unroll
            for (int i = 0; i < 2; i++)
                #pragma unroll
                for (int j = 0; j < 4; j++)
                    sa[i][j] = __builtin_amdgcn_mfma_f32_16x16x32_bf16(af[i][ks], bfr[j], sa[i][j], 0, 0, 0);
        }

        #pragma unroll
        for (int i = 0; i < 2; i++) {
            #pragma unroll
            for (int r = 0; r < 4; r++) {
                int t = t0 + w * 32 + i * 16 + (l >> 4) * 4 + r;
                float pv[4];
                float rmax = -1e30f;
                #pragma unroll
                for (int j = 0; j < 4; j++) {
                    int s = s0 + j * 16 + (l & 15);
                    float v = sa[i][j][r] * 0.125f;
                    v = (s <= t) ? v : -1e30f;
                    pv[j] = v;
                    rmax = fmaxf(rmax, v);
                }
                #pragma unroll
                for (int msk = 1; msk < 16; msk <<= 1)
                    rmax = fmaxf(rmax, __shfl_xor(rmax, msk));
                float mo = mrow[i][r];
                float mn = fmaxf(mo, rmax);
                float fac = __expf(mo - mn);
                float ls = 0.f;
                int prow = w * 32 + i * 16 + (l >> 4) * 4 + r;
                #pragma unroll
                for (int j = 0; j < 4; j++) {
                    float e = __expf(pv[j] - mn);
                    ls += e;
                    int cb = (j * 32 + (l & 15) * 2) ^ ((prow & 7) << 4);
                    *(__hip_bfloat16*)((char*)Ps + prow * 128 + cb) = __float2bfloat16(e);
                }
                #pragma unroll
                for (int msk = 1; msk < 16; msk <<= 1)
                    ls += __shfl_xor(ls, msk);
                mrow[i][r] = mn;
                lrow[i][r] = lrow[i][r] * fac + ls;
                #pragma unroll
                for (int jd = 0; jd < 4; jd++)
                    acc_o[i][jd][r] *= fac;
            }
        }

        #pragma unroll
        for (int ks = 0; ks < 2; ks++) {
            bf16x8 pa[2], vf[4];
            #pragma unroll
            for (int i = 0; i < 2; i++) {
                int row = w * 32 + i * 16 + (l & 15);
                int cb = (ks * 64 + (l >> 4) * 16) ^ ((row & 7) << 4);
                pa[i] = *(const bf16x8*)((const char*)Ps + row * 128 + cb);
            }
            #pragma unroll
            for (int jd = 0; jd < 4; jd++) {
                int row = jd * 16 + (l & 15);
                int cb = (ks * 64 + (l >> 4) * 16) ^ ((row & 7) << 4);
                vf[jd] = *(const bf16x8*)((const char*)Vs[p] + row * 128 + cb);
            }
            #pragma unroll
            for (int i = 0; i < 2; i++)
                #pragma unroll
                for (int jd = 0; jd < 4; jd++)
                    acc_o[i][jd] = __builtin_amdgcn_mfma_f32_16x16x32_bf16(pa[i], vf[jd], acc_o[i][jd], 0, 0, 0);
        }
        p ^= 1;
    }

    int b = blockIdx.z, hh = blockIdx.y;
    #pragma unroll
    for (int i = 0; i < 2; i++) {
        #pragma unroll
        for (int r = 0; r < 4; r++) {
            float inv = 1.f / lrow[i][r];
            int t = t0 + w * 32 + i * 16 + (l >> 4) * 4 + r;
            #pragma unroll
            for (int jd = 0; jd < 4; jd++) {
                int d = jd * 16 + (l & 15);
                oc[((size_t)(b * TT + t)) * CC + hh * DD + d] =
                    __float2bfloat16(acc_o[i][jd][r] * inv);
            }
        }
    }
}

// ---------------- hb = bf16(LN(rb)) — wave-reduce (2 barriers); rb = pre-LN residual bf16
__global__ __launch_bounds__(256) void resid_ln(__hip_bfloat16* __restrict__ hb,
                                                const __hip_bfloat16* __restrict__ rb,
                                                const float* __restrict__ g,
                                                const float* __restrict__ bta) {
    int row = blockIdx.x;
    int tid = threadIdx.x;
    int l = tid & 63, w = tid >> 6;
    __shared__ float pa[4], pb[4];
    float x[3];
    float s = 0.f;
    #pragma unroll
    for (int i = 0; i < 3; i++) {
        int c = tid + i * 256;
        x[i] = __bfloat162float(rb[(size_t)row * CC + c]);
        s += x[i];
    }
    #pragma unroll
    for (int msk = 1; msk < 64; msk <<= 1) s += __shfl_xor(s, msk);
    if (l == 0) pa[w] = s;
    __syncthreads();
    float mean = (pa[0] + pa[1] + pa[2] + pa[3]) * (1.f / CC);
    float s2 = 0.f;
    #pragma unroll
    for (int i = 0; i < 3; i++) { float dd = x[i] - mean; s2 += dd * dd; }
    #pragma unroll
    for (int msk = 1; msk < 64; msk <<= 1) s2 += __shfl_xor(s2, msk);
    if (l == 0) pb[w] = s2;
    __syncthreads();
    float inv = rsqrtf((pb[0] + pb[1] + pb[2] + pb[3]) * (1.f / CC) + 1e-5f);
    #pragma unroll
    for (int i = 0; i < 3; i++) {
        int c = tid + i * 256;
        hb[(size_t)row * CC + c] = __float2bfloat16((x[i] - mean) * inv * g[c] + bta[c]);
    }
}

__global__ __launch_bounds__(256) void loss_reduce(const float* __restrict__ rl,
                                                   float* __restrict__ out) {
    int tid = threadIdx.x;
    __shared__ float red[256];
    float s = 0.f;
    for (int i = tid; i < MROWS; i += 256) s += rl[i];
    red[tid] = s; __syncthreads();
    for (int off = 128; off > 0; off >>= 1) {
        if (tid < off) red[tid] += red[tid + off];
        __syncthreads();
    }
    if (tid == 0) out[0] = red[0] * (1.f / MROWS);
}

extern "C" void kernel_launch(void* const* d_in, const int* in_sizes, int n_in,
                              void* d_out, int out_size, void* d_ws, size_t ws_size,
                              hipStream_t stream) {
    const int*   x     = (const int*)d_in[0];
    const int*   y     = (const int*)d_in[1];
    const float* tok   = (const float*)d_in[2];
    const float* pos   = (const float*)d_in[3];
    const float* Wk    = (const float*)d_in[4];
    const float* Wq    = (const float*)d_in[5];
    const float* Wv    = (const float*)d_in[6];
    const float* Wproj = (const float*)d_in[7];
    const float* bproj = (const float*)d_in[8];
    const float* ln1g  = (const float*)d_in[9];
    const float* ln1b  = (const float*)d_in[10];
    const float* W1    = (const float*)d_in[11];
    const float* b1    = (const float*)d_in[12];
    const float* W2    = (const float*)d_in[13];
    const float* b2    = (const float*)d_in[14];
    const float* ln2g  = (const float*)d_in[15];
    const float* ln2b  = (const float*)d_in[16];
    const float* Wlm   = (const float*)d_in[17];
    const float* blm   = (const float*)d_in[18];

    float* logits = (float*)d_out;
    float* lossp  = (float*)d_out + ((size_t)out_size - 1);

    char* p = (char*)d_ws;
    auto alloc = [&](size_t bytes) { char* r = p; p += (bytes + 255) & ~255ULL; return r; };
    const size_t S_HC = (size_t)MROWS * CC;

    float* rl   = (float*)alloc(MROWS * 4);
    float* pm   = (float*)alloc((size_t)MROWS * NPART * 4);
    float* ps   = (float*)alloc((size_t)MROWS * NPART * 4);
    __hip_bfloat16* tmpb = (__hip_bfloat16*)alloc(S_HC * 2);   // pre-LN residual
    __hip_bfloat16* kbb  = (__hip_bfloat16*)alloc(S_HC * 2);
    __hip_bfloat16* qbb  = (__hip_bfloat16*)alloc(S_HC * 2);
    __hip_bfloat16* vtb  = (__hip_bfloat16*)alloc(S_HC * 2);
    __hip_bfloat16* hb   = (__hip_bfloat16*)alloc(S_HC * 2);
    __hip_bfloat16* ocb  = (__hip_bfloat16*)alloc(S_HC * 2);
    __hip_bfloat16* ff1b = (__hip_bfloat16*)alloc((size_t)MROWS * FFH * 2);
    __hip_bfloat16* kT   = (__hip_bfloat16*)alloc((size_t)LL * CC * CC * 2);
    __hip_bfloat16* qT   = (__hip_bfloat16*)alloc((size_t)LL * CC * CC * 2);
    __hip_bfloat16* vT   = (__hip_bfloat16*)alloc((size_t)LL * CC * CC * 2);
    __hip_bfloat16* pT   = (__hip_bfloat16*)alloc((size_t)LL * CC * CC * 2);
    __hip_bfloat16* w1T  = (__hip_bfloat16*)alloc((size_t)LL * CC * FFH * 2);
    __hip_bfloat16* w2T  = (__hip_bfloat16*)alloc((size_t)LL * FFH * CC * 2);
    __hip_bfloat16* lmT  = (__hip_bfloat16*)alloc((size_t)VPAD2 * CC * 2);

    dim3 blk(256);

    cvtT_qkv<<<dim3(24, 2, 3 * 144), blk, 0, stream>>>(Wk, Wq, Wv, kT, qT, vT);
    cvtT_mat<<<dim3(24, 24, LL), blk, 0, stream>>>(Wproj, pT, CC, CC,
                                                   (size_t)CC * CC, (size_t)CC * CC);
    cvtT_mat<<<dim3(96, 24, LL), blk, 0, stream>>>(W1, w1T, CC, FFH,
                                                   (size_t)CC * FFH, (size_t)FFH * CC);
    cvtT_mat<<<dim3(24, 96, LL), blk, 0, stream>>>(W2, w2T, FFH, CC,
                                                   (size_t)FFH * CC, (size_t)CC * FFH);
    cvtT_mat<<<dim3(VPAD2 / 32, 24, 1), blk, 0, stream>>>(Wlm, lmT, CC, VV, 0, 0);

    embed_kernel<<<dim3((MROWS * CC + 255) / 256), blk, 0, stream>>>(x, tok, pos, hb);

    for (int l = 0; l < LL; l++) {
        const __hip_bfloat16* kT_l = kT + (size_t)l * CC * CC;
        const __hip_bfloat16* qT_l = qT + (size_t)l * CC * CC;
        const __hip_bfloat16* vT_l = vT + (size_t)l * CC * CC;
        const __hip_bfloat16* pT_l = pT + (size_t)l * CC * CC;
        const __hip_bfloat16* w1T_l = w1T + (size_t)l * CC * FFH;
        const __hip_bfloat16* w2T_l = w2T + (size_t)l * FFH * CC;

        gemm_qkv_n64<<<dim3(CC / 64, MROWS / 128, 3), blk, 0, stream>>>(
            hb, kT_l, qT_l, vT_l, kbb, qbb, vtb);
        attn_mfma<<<dim3(TT / QBLK, HH, BB), blk, 0, stream>>>(kbb, qbb, vtb, ocb);
        // proj + residual add (hb) -> tmpb (bf16 pre-LN residual)
        gemm_mfma_n64r<<<dim3(CC / 64, MROWS / 128), blk, 0, stream>>>(
            ocb, pT_l, bproj + (size_t)l * CC, hb, tmpb, MROWS, CC, CC);
        resid_ln<<<dim3(MROWS), blk, 0, stream>>>(hb, tmpb, ln1g + (size_t)l * CC,
                                                  ln1b + (size_t)l * CC);
        gemm_mfma<<<dim3(FFH / 128, MROWS / 128), blk, 0, stream>>>(
            hb, w1T_l, b1 + (size_t)l * FFH, ff1b, MROWS, FFH, CC, 1);
        // ffn2 + residual add (hb) -> tmpb
        gemm_mfma_n64r<<<dim3(CC / 64, MROWS / 128), blk, 0, stream>>>(
            ff1b, w2T_l, b2 + (size_t)l * CC, hb, tmpb, MROWS, CC, FFH);
        resid_ln<<<dim3(MROWS), blk, 0, stream>>>(hb, tmpb, ln2g + (size_t)l * CC,
                                                  ln2b + (size_t)l * CC);
    }

    lm_head_mfma256<<<dim3(MROWS / 256, VPAD2 / 256), dim3(512), 0, stream>>>(
        hb, lmT, blm, logits, pm, ps);
    nll_combine<<<dim3(MROWS), blk, 0, stream>>>(pm, ps, logits, y, rl);
    loss_reduce<<<dim3(1), blk, 0, stream>>>(rl, lossp);
}